// Round 1
// 423.131 us; speedup vs baseline: 1.0185x; 1.0185x over previous
//
#include <hip/hip_runtime.h>
#include <stdint.h>
#include <stddef.h>

// Problem constants
#define T_ 512
#define B_ 256
#define IN_ 292
#define H_ 128
#define G4_ 512     // 4*H
#define TB_ 131072  // T_*B_
#define LCH 32      // time-chunk length for the segment scan
#define NCH 16      // number of chunks (T_/LCH)
#define KP_ 320     // K padded to 10*32

typedef short bf16x8 __attribute__((ext_vector_type(8)));
typedef float f32x4 __attribute__((ext_vector_type(4)));

__device__ __forceinline__ unsigned short f2bf(float f) {
  unsigned u = __float_as_uint(f);
  u += 0x7FFFu + ((u >> 16) & 1u);   // RTNE
  return (unsigned short)(u >> 16);
}
__device__ __forceinline__ float bf2f(unsigned short s) {
  return __uint_as_float(((unsigned)s) << 16);
}
// two fp32 -> packed bf16 pair (round-half-up). 1.5 VALU ops/elem.
__device__ __forceinline__ unsigned bfpack2(float a, float b) {
  unsigned ua = __float_as_uint(a) + 0x8000u;
  unsigned ub = __float_as_uint(b) + 0x8000u;
  return __builtin_amdgcn_perm(ub, ua, 0x07060302u);  // [ub.hi16 : ua.hi16]
}
__device__ __forceinline__ float sigf(float x) {
  return __builtin_amdgcn_rcpf(1.0f + __expf(-x));
}
__device__ __forceinline__ float tanhf_(float x) {
  return 1.0f - 2.0f * __builtin_amdgcn_rcpf(__expf(2.0f * x) + 1.0f);
}
// LDS-only barrier: lgkmcnt(0)+s_barrier, leaves global loads/stores in flight.
__device__ __forceinline__ void barrier_lds() {
  asm volatile("s_waitcnt lgkmcnt(0)\n\ts_barrier" ::: "memory");
}
// load one lane's 4 cell-quads (32 B contiguous): pr[r] = {i,f,g,o} of cell r.
__device__ __forceinline__ void load_pr(const unsigned short* p, ushort4* pr) {
  union { uint4 v; ushort4 s[2]; } a, b;
  a.v = *(const uint4*)p;
  b.v = *(const uint4*)(p + 8);
  pr[0] = a.s[0]; pr[1] = a.s[1]; pr[2] = b.s[0]; pr[3] = b.s[1];
}

// ---------------------------------------------------------------------------
// K0w: W_ih fp32 [512][292] -> Wb2 bf16 [512][320], ROW-REORDERED so that
// row jj = W_ih row (jj&3)*128 + (jj>>2)   (jj = cell*4 + gate).
// Also emits reordered bias2[jj] (fp32).
// ---------------------------------------------------------------------------
__global__ __launch_bounds__(256) void k0w_cvt(
    const float* __restrict__ Wih, const float* __restrict__ bih,
    const float* __restrict__ bhh, unsigned short* __restrict__ Wb,
    float* __restrict__ bias2) {
  const int g = blockIdx.x * 256 + threadIdx.x;
  const int jj = g / 40, s = g % 40;
  const int src = (jj & 3) * 128 + (jj >> 2);
  if (g < 512) {
    const int sb = (g & 3) * 128 + (g >> 2);
    bias2[g] = bih[sb] + bhh[sb];
  }
  float4 a = {0.f, 0.f, 0.f, 0.f}, b = {0.f, 0.f, 0.f, 0.f};
  const float* p = Wih + (size_t)src * IN_ + 8 * s;
  if (s < 36) { a = *(const float4*)p; b = *(const float4*)(p + 4); }
  else if (s == 36) { a = *(const float4*)p; }  // floats 288..291
  uint4 o;
  o.x = bfpack2(a.x, a.y); o.y = bfpack2(a.z, a.w);
  o.z = bfpack2(b.x, b.y); o.w = bfpack2(b.z, b.w);
  *(uint4*)&Wb[(size_t)jj * KP_ + 8 * s] = o;
}

// ---------------------------------------------------------------------------
// K1 v2: pre2[m][jj] (bf16) = x @ Wb2^T + bias2, jj = cell*4+gate.
// Occupancy-first restructure:
//  - 1024-thread blocks (16 waves), m-tile 128 x full jj 512.
//  - wave (wr,wc) owns m [64wr,64wr+64) x jj [64wc,64wc+64): acc[4][4] = 64
//    unified regs (vs 128 before). Target <=128 regs/wave -> 4 waves/SIMD
//    (50% occupancy) in one resident block; was ~256 regs -> 2 waves/SIMD.
//  - no W-frag prefetch regs: Wb is 320 KB, L2-hot; TLP at 4 waves/SIMD
//    hides the ~250 cyc L2 latency.
//  - x: fp32 global->reg (2-deep ring, 1 float4/lane), pack bf16 -> dbuf LDS,
//    lgkm-only barriers (global loads stay in flight across barriers).
//  - epilogue staged through LDS: 8 stages x 16 full rows; every global
//    store is a full 1024B row written as lane-contiguous uint4 ->
//    WRITE_SIZE 193.5 MB -> ~137 MB (kills partial-line RMW).
// ---------------------------------------------------------------------------
__global__ __launch_bounds__(1024, 4) void k1_pregemm(
    const float* __restrict__ x, const unsigned short* __restrict__ Wb,
    const float* __restrict__ bias2, unsigned short* __restrict__ pre2) {
  __shared__ unsigned short xt[2][128 * 32];  // 16 KB (bf16 x-tiles, dbuf)
  __shared__ unsigned short ep[16 * 520];     // 16.25 KB epilogue (1040B rows)

  const int m0 = blockIdx.x * 128;
  const int tid = threadIdx.x;
  const int w = tid >> 6;       // 0..15
  const int wr = w >> 3;        // m half
  const int wc = w & 7;         // jj group
  const int lane = tid & 63;
  const int l15 = lane & 15;
  const int q = lane >> 4;

  // x staging: lane loads 1 float4; row = tid>>3 (0..127), col = (tid&7)*4
  const int xrow = tid >> 3;
  const int xcol = (tid & 7) * 4;
  const float* xbase = x + (size_t)(m0 + xrow) * IN_;

  f32x4 acc[4][4];
#pragma unroll
  for (int s = 0; s < 4; s++)
#pragma unroll
    for (int ms = 0; ms < 4; ms++) acc[s][ms] = (f32x4){0.f, 0.f, 0.f, 0.f};

  // 2-deep x register ring: xst[t&1] holds tile t's float4.
  float4 xst[2];
  xst[0] = *(const float4*)(xbase + xcol);
  xst[1] = *(const float4*)(xbase + 32 + xcol);
  {  // pack tile 0 -> xt[0]
    uint2 v;
    v.x = bfpack2(xst[0].x, xst[0].y);
    v.y = bfpack2(xst[0].z, xst[0].w);
    *(uint2*)&xt[0][xrow * 32 + xcol] = v;
  }
  barrier_lds();

#pragma unroll
  for (int it = 0; it < 10; it++) {
    // issue x load for tile it+2 into ring slot it&1 (tile it already packed)
    if (it + 2 <= 9) {
      const int tt = it + 2;
      if (tt < 9) {
        xst[it & 1] = *(const float4*)(xbase + 32 * tt + xcol);
      } else {  // tail tile: cols 288..291 valid only
        float4 z = {0.f, 0.f, 0.f, 0.f};
        xst[it & 1] = (xcol == 0) ? *(const float4*)(xbase + 288) : z;
      }
    }
    // W frags for this tile (global, L2-hot; no prefetch regs needed)
    bf16x8 af[4];
    const int kk = 32 * it;
#pragma unroll
    for (int s = 0; s < 4; s++)
      af[s] = *(const bf16x8*)&Wb[(size_t)(wc * 64 + 16 * s + l15) * KP_ + kk + q * 8];
    // x frags from LDS
    const unsigned short* xb = xt[it & 1];
    bf16x8 bfr[4];
#pragma unroll
    for (int ms = 0; ms < 4; ms++)
      bfr[ms] = *(const bf16x8*)&xb[(64 * wr + 16 * ms + l15) * 32 + q * 8];
#pragma unroll
    for (int s = 0; s < 4; s++)
#pragma unroll
      for (int ms = 0; ms < 4; ms++)
        acc[s][ms] = __builtin_amdgcn_mfma_f32_16x16x32_bf16(
            af[s], bfr[ms], acc[s][ms], 0, 0, 0);
    // pack tile it+1 (regs loaded last iter; latency covered by MFMAs)
    if (it < 9) {
      const float4 xv = xst[(it + 1) & 1];
      uint2 v;
      v.x = bfpack2(xv.x, xv.y);
      v.y = bfpack2(xv.z, xv.w);
      *(uint2*)&xt[(it + 1) & 1][xrow * 32 + xcol] = v;
    }
    barrier_lds();
  }

  // epilogue: 8 stages of 16 rows; stage st -> rows [16st, 16st+16).
  // Wave (wr,wc) contributes when wr == st>>2, writing acc[s][st&3].
  float4 bb[4];
#pragma unroll
  for (int s = 0; s < 4; s++)
    bb[s] = *(const float4*)&bias2[wc * 64 + 16 * s + 4 * q];

#pragma unroll
  for (int st = 0; st < 8; st++) {
    if ((st >> 2) == wr) {
      const int ms = st & 3;
#pragma unroll
      for (int s = 0; s < 4; s++) {
        uint2 v;
        v.x = bfpack2(acc[s][ms][0] + bb[s].x, acc[s][ms][1] + bb[s].y);
        v.y = bfpack2(acc[s][ms][2] + bb[s].z, acc[s][ms][3] + bb[s].w);
        // row l15 of this stage; byte = l15*1040 + wc*128 + s*32 + q*8
        *(uint2*)&ep[l15 * 520 + wc * 64 + s * 16 + q * 4] = v;
      }
    }
    barrier_lds();
    {  // wave w stores full row m0+16st+w (1024 B, lane-contiguous uint4)
      const int off = lane;  // 16-B units within the row
      uint4 v = *(const uint4*)&ep[w * 520 + off * 8];
      *(uint4*)&pre2[((size_t)(m0 + 16 * st + w) << 9) + off * 8] = v;
    }
    barrier_lds();  // reads done before next stage overwrites ep
  }
}

// ---------------------------------------------------------------------------
// Segment-scan LSTM (exact for any done; fast because P(reset)=0.5).
// pre2 layout: element m*512 + cell*4 + gate -> one 32B load per lane gives
// pr[r] = {i,f,g,o} of cell kcell+r.
// ---------------------------------------------------------------------------
__global__ __launch_bounds__(512) void k2a_chunk(
    const unsigned short* __restrict__ pre2, const float* __restrict__ Whh,
    const int* __restrict__ done, unsigned short* __restrict__ hidden,
    unsigned short* __restrict__ hfin, float* __restrict__ cfin) {
  __shared__ unsigned short hs[2][16 * 136];
  __shared__ int dns[LCH * 16];

  const int bg = blockIdx.x & 15;
  const int ck = blockIdx.x >> 4;
  const int t0 = ck * LCH;
  const int tid = threadIdx.x;
  const int w = tid >> 6;
  const int lane = tid & 63;
  const int l15 = lane & 15;
  const int q = lane >> 4;
  const int bglob = bg * 16 + l15;
  const int kcell = 16 * w + 4 * q;
  const int kq16 = kcell * 4;  // element offset of this lane's 4 cell-quads

  {
    const int r = tid >> 4, c = tid & 15;
    dns[tid] = done[(size_t)(t0 + r) * B_ + bg * 16 + c];
  }

  bf16x8 wf[4][4];
#pragma unroll
  for (int tI = 0; tI < 4; tI++) {
    const int jg = 16 * (w + 8 * tI) + l15;
#pragma unroll
    for (int kc = 0; kc < 4; kc++) {
      const float* p = Whh + (size_t)jg * H_ + kc * 32 + q * 8;
      float4 u0 = *(const float4*)p;
      float4 u1 = *(const float4*)(p + 4);
      bf16x8 r;
      r[0]=(short)f2bf(u0.x); r[1]=(short)f2bf(u0.y); r[2]=(short)f2bf(u0.z); r[3]=(short)f2bf(u0.w);
      r[4]=(short)f2bf(u1.x); r[5]=(short)f2bf(u1.y); r[6]=(short)f2bf(u1.z); r[7]=(short)f2bf(u1.w);
      wf[tI][kc] = r;
    }
  }

  float c_[4] = {0.f, 0.f, 0.f, 0.f};
  {
    const int b = tid >> 5, k = (tid & 31) * 4;
    *(ushort4*)&hs[0][b * 136 + k] = (ushort4){0, 0, 0, 0};
  }
  bool vld = false;
  __syncthreads();

  ushort4 pr[4], prn[4];
  load_pr(pre2 + ((size_t)t0 * B_ + bglob) * G4_ + kq16, pr);
  load_pr(pre2 + ((size_t)(t0 + 1) * B_ + bglob) * G4_ + kq16, prn);

  ushort4 hw = {0, 0, 0, 0};
#pragma unroll 1
  for (int u = 0; u < LCH; u++) {
    const int t = t0 + u;
    ushort4 pr2[4];
    const int un = (u + 2 < LCH) ? u + 2 : LCH - 1;
    load_pr(pre2 + ((size_t)(t0 + un) * B_ + bglob) * G4_ + kq16, pr2);

    const int dn = dns[u * 16 + l15];
    vld = vld || (dn != 0);

    const unsigned short* hb = hs[u & 1];
    bf16x8 hf[4];
#pragma unroll
    for (int kc = 0; kc < 4; kc++) {
      bf16x8 v = *(const bf16x8*)&hb[l15 * 136 + kc * 32 + q * 8];
      if (dn) v = (bf16x8){0, 0, 0, 0, 0, 0, 0, 0};
      hf[kc] = v;
    }

    f32x4 acc[4];
#pragma unroll
    for (int tI = 0; tI < 4; tI++) acc[tI] = (f32x4){0.f, 0.f, 0.f, 0.f};
#pragma unroll
    for (int tI = 0; tI < 4; tI++)
#pragma unroll
      for (int kc = 0; kc < 4; kc++)
        acc[tI] = __builtin_amdgcn_mfma_f32_16x16x32_bf16(
            wf[tI][kc], hf[kc], acc[tI], 0, 0, 0);

    const float m = dn ? 0.0f : 1.0f;
    float hv[4];
#pragma unroll
    for (int r = 0; r < 4; r++) {
      const float iv = acc[0][r] + bf2f(pr[r].x);
      const float fv = acc[1][r] + bf2f(pr[r].y);
      const float gv = acc[2][r] + bf2f(pr[r].z);
      const float ov = acc[3][r] + bf2f(pr[r].w);
      float cc = c_[r] * m;
      cc = sigf(fv) * cc + sigf(iv) * tanhf_(gv);
      c_[r] = cc;
      hv[r] = sigf(ov) * tanhf_(cc);
    }
    uint2 hp = {bfpack2(hv[0], hv[1]), bfpack2(hv[2], hv[3])};
    hw = *(ushort4*)&hp;
    *(uint2*)&hs[(u + 1) & 1][l15 * 136 + kcell] = hp;
    if (vld)
      *(uint2*)&hidden[((size_t)t * B_ + bglob) * H_ + kcell] = hp;
#pragma unroll
    for (int tI = 0; tI < 4; tI++) { pr[tI] = prn[tI]; prn[tI] = pr2[tI]; }
    barrier_lds();
  }

  *(ushort4*)&hfin[((size_t)ck * B_ + bglob) * H_ + kcell] = hw;
  float4 cv = {c_[0], c_[1], c_[2], c_[3]};
  *(float4*)&cfin[((size_t)ck * B_ + bglob) * H_ + kcell] = cv;
}

__global__ __launch_bounds__(512) void k2b_par(
    const unsigned short* __restrict__ pre2, const float* __restrict__ Whh,
    const float* __restrict__ h0, const float* __restrict__ c0,
    const int* __restrict__ done, unsigned short* __restrict__ hidden,
    const unsigned short* __restrict__ hfin, const float* __restrict__ cfin,
    int* __restrict__ needfix) {
  __shared__ unsigned short hs[2][16 * 136];
  __shared__ int dns[LCH * 16];

  const int bg = blockIdx.x & 15;
  const int ck = blockIdx.x >> 4;
  const int t0 = ck * LCH;
  const int tid = threadIdx.x;
  const int w = tid >> 6;
  const int lane = tid & 63;
  const int l15 = lane & 15;
  const int q = lane >> 4;
  const int bglob = bg * 16 + l15;
  const int kcell = 16 * w + 4 * q;
  const int kq16 = kcell * 4;

  {
    const int r = tid >> 4, c = tid & 15;
    dns[tid] = done[(size_t)(t0 + r) * B_ + bg * 16 + c];
  }

  bf16x8 wf[4][4];
#pragma unroll
  for (int tI = 0; tI < 4; tI++) {
    const int jg = 16 * (w + 8 * tI) + l15;
#pragma unroll
    for (int kc = 0; kc < 4; kc++) {
      const float* p = Whh + (size_t)jg * H_ + kc * 32 + q * 8;
      float4 u0 = *(const float4*)p;
      float4 u1 = *(const float4*)(p + 4);
      bf16x8 r;
      r[0]=(short)f2bf(u0.x); r[1]=(short)f2bf(u0.y); r[2]=(short)f2bf(u0.z); r[3]=(short)f2bf(u0.w);
      r[4]=(short)f2bf(u1.x); r[5]=(short)f2bf(u1.y); r[6]=(short)f2bf(u1.z); r[7]=(short)f2bf(u1.w);
      wf[tI][kc] = r;
    }
  }

  float c_[4];
  {
    const int b = tid >> 5, k = (tid & 31) * 4;
    if (ck == 0) {
      float4 hv = *(const float4*)(h0 + (size_t)(bg * 16 + b) * H_ + k);
      uint2 hp = {bfpack2(hv.x, hv.y), bfpack2(hv.z, hv.w)};
      *(uint2*)&hs[0][b * 136 + k] = hp;
      float4 cv = *(const float4*)(c0 + (size_t)bglob * H_ + kcell);
      c_[0] = cv.x; c_[1] = cv.y; c_[2] = cv.z; c_[3] = cv.w;
    } else {
      ushort4 hv = *(const ushort4*)&hfin[((size_t)(ck - 1) * B_ + bg * 16 + b) * H_ + k];
      *(ushort4*)&hs[0][b * 136 + k] = hv;
      float4 cv = *(const float4*)&cfin[((size_t)(ck - 1) * B_ + bglob) * H_ + kcell];
      c_[0] = cv.x; c_[1] = cv.y; c_[2] = cv.z; c_[3] = cv.w;
    }
  }
  int cur = 0;
  bool act = true;
  __syncthreads();

  ushort4 pr[4];
  load_pr(pre2 + ((size_t)t0 * B_ + bglob) * G4_ + kq16, pr);

#pragma unroll 1
  for (int u = 0; u < LCH; u++) {
    const int t = t0 + u;
    const int dn = dns[u * 16 + l15];
    const bool nact = act && (dn == 0);
    if (__ballot(nact) == 0ULL) { act = false; break; }
    act = nact;

    ushort4 prn[4];
    const int un = (u + 1 < LCH) ? u + 1 : LCH - 1;
    load_pr(pre2 + ((size_t)(t0 + un) * B_ + bglob) * G4_ + kq16, prn);

    const unsigned short* hb = hs[cur];
    bf16x8 hf[4];
#pragma unroll
    for (int kc = 0; kc < 4; kc++)
      hf[kc] = *(const bf16x8*)&hb[l15 * 136 + kc * 32 + q * 8];

    f32x4 acc[4];
#pragma unroll
    for (int tI = 0; tI < 4; tI++) acc[tI] = (f32x4){0.f, 0.f, 0.f, 0.f};
#pragma unroll
    for (int tI = 0; tI < 4; tI++)
#pragma unroll
      for (int kc = 0; kc < 4; kc++)
        acc[tI] = __builtin_amdgcn_mfma_f32_16x16x32_bf16(
            wf[tI][kc], hf[kc], acc[tI], 0, 0, 0);

    float hv[4];
#pragma unroll
    for (int r = 0; r < 4; r++) {
      const float iv = acc[0][r] + bf2f(pr[r].x);
      const float fv = acc[1][r] + bf2f(pr[r].y);
      const float gv = acc[2][r] + bf2f(pr[r].z);
      const float ov = acc[3][r] + bf2f(pr[r].w);
      float cc = sigf(fv) * c_[r] + sigf(iv) * tanhf_(gv);
      c_[r] = cc;
      hv[r] = sigf(ov) * tanhf_(cc);
    }
    uint2 hp = {bfpack2(hv[0], hv[1]), bfpack2(hv[2], hv[3])};
    *(uint2*)&hs[cur ^ 1][l15 * 136 + kcell] = hp;
    if (act)
      *(uint2*)&hidden[((size_t)t * B_ + bglob) * H_ + kcell] = hp;
#pragma unroll
    for (int tI = 0; tI < 4; tI++) pr[tI] = prn[tI];
    barrier_lds();
    cur ^= 1;
  }

  if (tid == 0) needfix[blockIdx.x] = (__ballot(act) != 0ULL) ? 1 : 0;
}

// Sequential guard: exact fallback, expected to exit immediately.
__global__ __launch_bounds__(512) void k2c_guard(
    const unsigned short* __restrict__ pre2, const float* __restrict__ Whh,
    const float* __restrict__ h0, const float* __restrict__ c0,
    const int* __restrict__ done, unsigned short* __restrict__ hidden,
    const unsigned short* __restrict__ hfin, const float* __restrict__ cfin,
    const int* __restrict__ needfix) {
  const int bg = blockIdx.x;
  bool dirty = false;
  for (int c2 = 0; c2 < NCH - 1; c2++) dirty |= (needfix[c2 * 16 + bg] != 0);
  if (!dirty) return;

  __shared__ unsigned short hs[2][16 * 136];
  __shared__ int dns[T_ * 16];

  const int tid = threadIdx.x;
  const int w = tid >> 6;
  const int lane = tid & 63;
  const int l15 = lane & 15;
  const int q = lane >> 4;
  const int bglob = bg * 16 + l15;
  const int kcell = 16 * w + 4 * q;
  const int kq16 = kcell * 4;

  {
    const int* p = done + (size_t)tid * B_ + bg * 16;
    *(int4*)&dns[tid * 16]      = *(const int4*)(p);
    *(int4*)&dns[tid * 16 + 4]  = *(const int4*)(p + 4);
    *(int4*)&dns[tid * 16 + 8]  = *(const int4*)(p + 8);
    *(int4*)&dns[tid * 16 + 12] = *(const int4*)(p + 12);
  }

  bf16x8 wf[4][4];
#pragma unroll
  for (int tI = 0; tI < 4; tI++) {
    const int jg = 16 * (w + 8 * tI) + l15;
#pragma unroll
    for (int kc = 0; kc < 4; kc++) {
      const float* p = Whh + (size_t)jg * H_ + kc * 32 + q * 8;
      float4 u0 = *(const float4*)p;
      float4 u1 = *(const float4*)(p + 4);
      bf16x8 r;
      r[0]=(short)f2bf(u0.x); r[1]=(short)f2bf(u0.y); r[2]=(short)f2bf(u0.z); r[3]=(short)f2bf(u0.w);
      r[4]=(short)f2bf(u1.x); r[5]=(short)f2bf(u1.y); r[6]=(short)f2bf(u1.z); r[7]=(short)f2bf(u1.w);
      wf[tI][kc] = r;
    }
  }

  float c_[4];
  {
    float4 cv = *(const float4*)(c0 + (size_t)bglob * H_ + kcell);
    c_[0] = cv.x; c_[1] = cv.y; c_[2] = cv.z; c_[3] = cv.w;
    const int b = tid >> 5, k = (tid & 31) * 4;
    float4 hv = *(const float4*)(h0 + (size_t)(bg * 16 + b) * H_ + k);
    uint2 hp = {bfpack2(hv.x, hv.y), bfpack2(hv.z, hv.w)};
    *(uint2*)&hs[0][b * 136 + k] = hp;
  }
  int cur = 0;
  __syncthreads();

#pragma unroll 1
  for (int ck = 0; ck < NCH; ck++) {
    const int t0 = ck * LCH;
    bool act = true;

    ushort4 pr[4];
    load_pr(pre2 + ((size_t)t0 * B_ + bglob) * G4_ + kq16, pr);

#pragma unroll 1
    for (int u = 0; u < LCH; u++) {
      const int t = t0 + u;
      const int dn = dns[t * 16 + l15];
      const bool nact = act && (dn == 0);
      if (__ballot(nact) == 0ULL) { act = false; break; }
      act = nact;

      ushort4 prn[4];
      const int un = (u + 1 < LCH) ? u + 1 : LCH - 1;
      load_pr(pre2 + ((size_t)(t0 + un) * B_ + bglob) * G4_ + kq16, prn);

      const unsigned short* hb = hs[cur];
      bf16x8 hf[4];
#pragma unroll
      for (int kc = 0; kc < 4; kc++)
        hf[kc] = *(const bf16x8*)&hb[l15 * 136 + kc * 32 + q * 8];

      f32x4 acc[4];
#pragma unroll
      for (int tI = 0; tI < 4; tI++) acc[tI] = (f32x4){0.f, 0.f, 0.f, 0.f};
#pragma unroll
      for (int tI = 0; tI < 4; tI++)
#pragma unroll
        for (int kc = 0; kc < 4; kc++)
          acc[tI] = __builtin_amdgcn_mfma_f32_16x16x32_bf16(
              wf[tI][kc], hf[kc], acc[tI], 0, 0, 0);

      float hv[4];
#pragma unroll
      for (int r = 0; r < 4; r++) {
        const float iv = acc[0][r] + bf2f(pr[r].x);
        const float fv = acc[1][r] + bf2f(pr[r].y);
        const float gv = acc[2][r] + bf2f(pr[r].z);
        const float ov = acc[3][r] + bf2f(pr[r].w);
        float cc = sigf(fv) * c_[r] + sigf(iv) * tanhf_(gv);
        c_[r] = cc;
        hv[r] = sigf(ov) * tanhf_(cc);
      }
      uint2 hp = {bfpack2(hv[0], hv[1]), bfpack2(hv[2], hv[3])};
      *(uint2*)&hs[cur ^ 1][l15 * 136 + kcell] = hp;
      if (act)
        *(uint2*)&hidden[((size_t)t * B_ + bglob) * H_ + kcell] = hp;
#pragma unroll
      for (int tI = 0; tI < 4; tI++) pr[tI] = prn[tI];
      barrier_lds();
      cur ^= 1;
    }

    if (!act) {
      ushort4 hv = *(const ushort4*)&hfin[((size_t)ck * B_ + bglob) * H_ + kcell];
      float4 cv = *(const float4*)&cfin[((size_t)ck * B_ + bglob) * H_ + kcell];
      c_[0] = cv.x; c_[1] = cv.y; c_[2] = cv.z; c_[3] = cv.w;
      *(ushort4*)&hs[cur][l15 * 136 + kcell] = hv;
    }
    barrier_lds();
  }
}

// ---------------------------------------------------------------------------
// K3: out[T*B][13] = hidden @ [W_pi; W_v]^T + [b_pi; b_v]   (unchanged)
// ---------------------------------------------------------------------------
__global__ __launch_bounds__(256) void k3_head(
    const unsigned short* __restrict__ hidden, const float* __restrict__ Wpi,
    const float* __restrict__ bpi, const float* __restrict__ Wv,
    const float* __restrict__ bv, float* __restrict__ out) {
  __shared__ unsigned short hs3[64 * 136];
  __shared__ float bias_s[16];

  const int tid = threadIdx.x;
  const int w = tid >> 6;
  const int lane = tid & 63;
  const int l15 = lane & 15;
  const int q = lane >> 4;
  const int m0 = blockIdx.x * 64;

  if (tid < 16) bias_s[tid] = (tid < 12) ? bpi[tid] : ((tid == 12) ? bv[0] : 0.f);

  bf16x8 wf3[4];
#pragma unroll
  for (int kc = 0; kc < 4; kc++) {
    float4 u0 = {0.f, 0.f, 0.f, 0.f}, u1 = {0.f, 0.f, 0.f, 0.f};
    if (l15 < 12) {
      const float* p = Wpi + (size_t)l15 * H_ + kc * 32 + q * 8;
      u0 = *(const float4*)p; u1 = *(const float4*)(p + 4);
    } else if (l15 == 12) {
      const float* p = Wv + kc * 32 + q * 8;
      u0 = *(const float4*)p; u1 = *(const float4*)(p + 4);
    }
    bf16x8 r;
    r[0]=(short)f2bf(u0.x); r[1]=(short)f2bf(u0.y); r[2]=(short)f2bf(u0.z); r[3]=(short)f2bf(u0.w);
    r[4]=(short)f2bf(u1.x); r[5]=(short)f2bf(u1.y); r[6]=(short)f2bf(u1.z); r[7]=(short)f2bf(u1.w);
    wf3[kc] = r;
  }

  {
    const int row = tid >> 2, ks = (tid & 3) * 32;
    const unsigned short* p = hidden + (size_t)(m0 + row) * H_ + ks;
#pragma unroll
    for (int i = 0; i < 4; i++)
      *(uint4*)&hs3[row * 136 + ks + i * 8] = *(const uint4*)(p + i * 8);
  }
  __syncthreads();

  f32x4 acc = (f32x4){0.f, 0.f, 0.f, 0.f};
#pragma unroll
  for (int kc = 0; kc < 4; kc++) {
    bf16x8 hf = *(bf16x8*)&hs3[(16 * w + l15) * 136 + kc * 32 + q * 8];
    acc = __builtin_amdgcn_mfma_f32_16x16x32_bf16(wf3[kc], hf, acc, 0, 0, 0);
  }

  const float4 bb = *(float4*)&bias_s[4 * q];
  const int m = m0 + 16 * w + l15;
  const size_t ro = (size_t)m * 13;
  float v0 = acc[0] + bb.x, v1 = acc[1] + bb.y, v2 = acc[2] + bb.z, v3 = acc[3] + bb.w;
  if (q < 3) {
    out[ro + 4 * q + 0] = v0;
    out[ro + 4 * q + 1] = v1;
    out[ro + 4 * q + 2] = v2;
    out[ro + 4 * q + 3] = v3;
  } else {
    out[ro + 12] = v0;
  }
}

// ---------------------------------------------------------------------------
// Workspace (ws, 167.8 MB):
//   pre2   bf16 [131072][512] @ 0            (cell-major-quad layout)
//   hidden bf16 [131072][128] @ 134,217,728
// Scratch in d_out (6.5 MB, overwritten by K3 at the end):
//   Wb2 bf16 [512][320] @ 0 (320 KB)   bias2 fp32 [512] @ 512 KB
//   hfin @ 1 MB, cfin @ 2 MB, needfix @ 4 MB
// ---------------------------------------------------------------------------
extern "C" void kernel_launch(void* const* d_in, const int* in_sizes, int n_in,
                              void* d_out, int out_size, void* d_ws, size_t ws_size,
                              hipStream_t stream) {
  const float* x    = (const float*)d_in[0];
  const int* done   = (const int*)d_in[1];
  const float* h0   = (const float*)d_in[2];
  const float* c0   = (const float*)d_in[3];
  const float* Wih  = (const float*)d_in[4];
  const float* Whh  = (const float*)d_in[5];
  const float* bih  = (const float*)d_in[6];
  const float* bhh  = (const float*)d_in[7];
  const float* Wpi  = (const float*)d_in[8];
  const float* bpi  = (const float*)d_in[9];
  const float* Wv   = (const float*)d_in[10];
  const float* bv   = (const float*)d_in[11];
  (void)in_sizes; (void)n_in; (void)out_size; (void)ws_size;

  unsigned short* pre2 = (unsigned short*)d_ws;
  unsigned short* hidden = pre2 + (size_t)TB_ * G4_;
  unsigned short* Wb   = (unsigned short*)d_out;
  float* bias2         = (float*)((char*)d_out + (512u << 10));
  unsigned short* hfin = (unsigned short*)((char*)d_out + (1u << 20));
  float* cfin          = (float*)((char*)d_out + (2u << 20));
  int* needfix         = (int*)((char*)d_out + (4u << 20));
  float* out = (float*)d_out;

  k0w_cvt<<<80, 256, 0, stream>>>(Wih, bih, bhh, Wb, bias2);
  k1_pregemm<<<TB_ / 128, 1024, 0, stream>>>(x, Wb, bias2, pre2);
  k2a_chunk<<<256, 512, 0, stream>>>(pre2, Whh, done, hidden, hfin, cfin);
  k2b_par<<<256, 512, 0, stream>>>(pre2, Whh, h0, c0, done, hidden, hfin, cfin, needfix);
  k2c_guard<<<16, 512, 0, stream>>>(pre2, Whh, h0, c0, done, hidden, hfin, cfin, needfix);
  k3_head<<<TB_ / 64, 256, 0, stream>>>(hidden, Wpi, bpi, Wv, bv, out);
}

// Round 2
// 400.405 us; speedup vs baseline: 1.0763x; 1.0568x over previous
//
#include <hip/hip_runtime.h>
#include <stdint.h>
#include <stddef.h>

// Problem constants
#define T_ 512
#define B_ 256
#define IN_ 292
#define H_ 128
#define G4_ 512     // 4*H
#define TB_ 131072  // T_*B_
#define LCH 32      // time-chunk length for the segment scan
#define NCH 16      // number of chunks (T_/LCH)
#define KP_ 320     // K padded to 10*32

typedef short bf16x8 __attribute__((ext_vector_type(8)));
typedef float f32x4 __attribute__((ext_vector_type(4)));

__device__ __forceinline__ unsigned short f2bf(float f) {
  unsigned u = __float_as_uint(f);
  u += 0x7FFFu + ((u >> 16) & 1u);   // RTNE
  return (unsigned short)(u >> 16);
}
__device__ __forceinline__ float bf2f(unsigned short s) {
  return __uint_as_float(((unsigned)s) << 16);
}
// two fp32 -> packed bf16 pair (round-half-up). 1.5 VALU ops/elem.
__device__ __forceinline__ unsigned bfpack2(float a, float b) {
  unsigned ua = __float_as_uint(a) + 0x8000u;
  unsigned ub = __float_as_uint(b) + 0x8000u;
  return __builtin_amdgcn_perm(ub, ua, 0x07060302u);  // [ub.hi16 : ua.hi16]
}
__device__ __forceinline__ float sigf(float x) {
  return __builtin_amdgcn_rcpf(1.0f + __expf(-x));
}
__device__ __forceinline__ float tanhf_(float x) {
  return 1.0f - 2.0f * __builtin_amdgcn_rcpf(__expf(2.0f * x) + 1.0f);
}
// LDS-only barrier: lgkmcnt(0)+s_barrier, leaves global loads/stores in flight.
__device__ __forceinline__ void barrier_lds() {
  asm volatile("s_waitcnt lgkmcnt(0)\n\ts_barrier" ::: "memory");
}
// load one lane's 4 cell-quads (32 B contiguous): pr[r] = {i,f,g,o} of cell r.
__device__ __forceinline__ void load_pr(const unsigned short* p, ushort4* pr) {
  union { uint4 v; ushort4 s[2]; } a, b;
  a.v = *(const uint4*)p;
  b.v = *(const uint4*)(p + 8);
  pr[0] = a.s[0]; pr[1] = a.s[1]; pr[2] = b.s[0]; pr[3] = b.s[1];
}

// ---------------------------------------------------------------------------
// K0w v3: W_ih fp32 [512][292] -> Wf, FRAG-MAJOR bf16 layout:
//   Wf[((g16*10 + it)*64 + lane)*8 .. +8] = row jj = 16*g16 + (lane&15),
//   k = it*32 + (lane>>4)*8 .. +8, with jj -> W_ih row (jj&3)*128 + (jj>>2)
//   (jj = cell*4 + gate). Each k1 af-load is 64 lanes x 16B fully contiguous
//   (was a 16-line stride-640B gather). Also emits reordered bias2[jj] fp32.
// ---------------------------------------------------------------------------
__global__ __launch_bounds__(256) void k0w_cvt(
    const float* __restrict__ Wih, const float* __restrict__ bih,
    const float* __restrict__ bhh, unsigned short* __restrict__ Wf,
    float* __restrict__ bias2) {
  const int g = blockIdx.x * 256 + threadIdx.x;  // 0..20479
  const int lane = g & 63;
  const int rest = g >> 6;          // 0..319
  const int it = rest % 10;
  const int g16 = rest / 10;        // 0..31
  const int jj = g16 * 16 + (lane & 15);
  const int src = (jj & 3) * 128 + (jj >> 2);
  const int c0 = it * 32 + (lane >> 4) * 8;
  if (g < 512) {
    const int sb = (g & 3) * 128 + (g >> 2);
    bias2[g] = bih[sb] + bhh[sb];
  }
  float4 a = {0.f, 0.f, 0.f, 0.f}, b = {0.f, 0.f, 0.f, 0.f};
  const float* p = Wih + (size_t)src * IN_ + c0;
  if (c0 + 8 <= IN_) { a = *(const float4*)p; b = *(const float4*)(p + 4); }
  else if (c0 < IN_) { a = *(const float4*)p; }  // c0==288: cols 288..291
  uint4 o;
  o.x = bfpack2(a.x, a.y); o.y = bfpack2(a.z, a.w);
  o.z = bfpack2(b.x, b.y); o.w = bfpack2(b.z, b.w);
  *(uint4*)&Wf[(size_t)g * 8] = o;  // g == (g16*10+it)*64 + lane
}

// ---------------------------------------------------------------------------
// K1 v3: pre2[m][jj] (bf16) = x @ W^T + bias2, jj = cell*4+gate.
// Serialization fixes (round-1 post-mortem):
//  - 512-thr blocks (8 waves; 256-reg cap) -> room for W prefetch again.
//  - wave w: ALL 128 m-rows x jj[64w,64w+64): acc[4][8]=128 AGPR, af 16+16
//    arch VGPR. No W redundancy across waves (32 KB/iter/CU from L2).
//  - frag-major Wf: af load = 1 KB contiguous per instr (no gathers).
//  - issue order per iter: [af-prefetch(4); x(git+2)(2)] so consuming af
//    waits vmcnt(6) and NEVER drains the x HBM stream (round-1 bug: x was
//    issued first, af-wait drained it -> ~900cy HBM latency every iter).
//  - persistent grid 256 x 4 m-tiles: epilogue stores of tile j overlap
//    tile j+1 GEMM; x ring flows continuously across tile boundaries.
//  - xt rows padded to 40 ushorts (80 B): 8-way bank conflict -> ~2-way.
//  - epilogue: 2 stages x 64 rows via ep LDS; full 1KB-row stores (4
//    barriers/tile, was 16).
// ---------------------------------------------------------------------------
__device__ __forceinline__ void k1_xissue(
    const float* __restrict__ x, int bid4, int xrow, int xcq, int g2,
    float4* xa, float4* xbv) {
  const int jx = g2 / 10, itx = g2 % 10;
  const float* p = x + (size_t)((bid4 + jx) * 128 + xrow) * IN_ + itx * 32 + xcq;
  const float4 z = {0.f, 0.f, 0.f, 0.f};
  if (itx < 9) {
    xa[g2 & 1] = *(const float4*)p;
    xbv[g2 & 1] = *(const float4*)(p + 4);
  } else {  // tail tile: cols 288..291 only (never read past row end)
    xa[g2 & 1] = (xcq == 0) ? *(const float4*)p : z;
    xbv[g2 & 1] = z;
  }
}

__global__ __launch_bounds__(512, 2) void k1_pregemm(
    const float* __restrict__ x, const unsigned short* __restrict__ Wf,
    const float* __restrict__ bias2, unsigned short* __restrict__ pre2) {
  __shared__ unsigned short xt[2][128 * 40];  // 20 KB bf16 x-tiles, padded
  __shared__ unsigned short ep[64 * 520];     // 65 KB epilogue staging

  const int tid = threadIdx.x;
  const int w = tid >> 6;        // 0..7: jj group [64w, 64w+64)
  const int lane = tid & 63;
  const int l15 = lane & 15;
  const int q = lane >> 4;
  const int bid4 = blockIdx.x * 4;

  // x staging: thread -> row tid>>2 (0..127), k-cols (tid&3)*8 .. +7
  const int xrow = tid >> 2;
  const int xcq = (tid & 3) * 8;

  // W frag base for this wave: af(s,it) at wfbase + (s*10+it)*512 ushorts
  const unsigned short* wfbase = Wf + ((size_t)(4 * w) * 10 * 64 + lane) * 8;

  f32x4 acc[4][8];
#pragma unroll
  for (int s = 0; s < 4; s++)
#pragma unroll
    for (int ms = 0; ms < 8; ms++) acc[s][ms] = (f32x4){0.f, 0.f, 0.f, 0.f};

  float4 xa[2], xbv[2];  // 2-deep x register ring (~1 iter in flight)
  k1_xissue(x, bid4, xrow, xcq, 0, xa, xbv);
  k1_xissue(x, bid4, xrow, xcq, 1, xa, xbv);
  bf16x8 af[4];
#pragma unroll
  for (int s = 0; s < 4; s++)
    af[s] = *(const bf16x8*)(wfbase + (s * 10 + 0) * 512);
  {  // pack tile 0 -> xt[0]
    uint4 v;
    v.x = bfpack2(xa[0].x, xa[0].y); v.y = bfpack2(xa[0].z, xa[0].w);
    v.z = bfpack2(xbv[0].x, xbv[0].y); v.w = bfpack2(xbv[0].z, xbv[0].w);
    *(uint4*)&xt[0][xrow * 40 + xcq] = v;
  }
  barrier_lds();

#pragma unroll 1
  for (int git = 0; git < 40; ++git) {
    const int it = git % 10;
    // 1) prefetch next-iter W frags (issued FIRST: af-consume = vmcnt(6))
    bf16x8 afn[4];
    if (git < 39) {
      const int nit = (it == 9) ? 0 : it + 1;
#pragma unroll
      for (int s = 0; s < 4; s++)
        afn[s] = *(const bf16x8*)(wfbase + (s * 10 + nit) * 512);
    }
    // 2) issue x for git+2 (stays in flight across barriers & af-waits)
    if (git + 2 < 40) k1_xissue(x, bid4, xrow, xcq, git + 2, xa, xbv);
    // 3) x frags from padded LDS
    const unsigned short* xb = xt[git & 1];
    bf16x8 bfr[8];
#pragma unroll
    for (int ms = 0; ms < 8; ms++)
      bfr[ms] = *(const bf16x8*)&xb[(16 * ms + l15) * 40 + q * 8];
    // 4) 32 MFMA
#pragma unroll
    for (int s = 0; s < 4; s++)
#pragma unroll
      for (int ms = 0; ms < 8; ms++)
        acc[s][ms] = __builtin_amdgcn_mfma_f32_16x16x32_bf16(
            af[s], bfr[ms], acc[s][ms], 0, 0, 0);
    // 5) pack tile git+1 (loaded last iter; latency covered by MFMAs)
    if (git < 39) {
      const float4 A = xa[(git + 1) & 1], Bv = xbv[(git + 1) & 1];
      uint4 v;
      v.x = bfpack2(A.x, A.y); v.y = bfpack2(A.z, A.w);
      v.z = bfpack2(Bv.x, Bv.y); v.w = bfpack2(Bv.z, Bv.w);
      *(uint4*)&xt[(git + 1) & 1][xrow * 40 + xcq] = v;
    }
#pragma unroll
    for (int s = 0; s < 4; s++) af[s] = afn[s];
    barrier_lds();

    if (it == 9) {
      // -------- epilogue for m-tile j = git/10: rows m0..m0+127 ----------
      const int m0 = (bid4 + git / 10) * 128;
      float4 bb[4];
#pragma unroll
      for (int s = 0; s < 4; s++)
        bb[s] = *(const float4*)&bias2[64 * w + 16 * s + 4 * q];
#pragma unroll
      for (int st = 0; st < 2; ++st) {
        // every wave writes its jj-cols for rows [64st, 64st+64)
#pragma unroll
        for (int mm = 0; mm < 4; ++mm) {
          const int ms = 4 * st + mm;
#pragma unroll
          for (int s = 0; s < 4; ++s) {
            uint2 v;
            v.x = bfpack2(acc[s][ms][0] + bb[s].x, acc[s][ms][1] + bb[s].y);
            v.y = bfpack2(acc[s][ms][2] + bb[s].z, acc[s][ms][3] + bb[s].w);
            *(uint2*)&ep[(16 * mm + l15) * 520 + 64 * w + 16 * s + 4 * q] = v;
          }
        }
        barrier_lds();
        // full-row stores: wave w, pass p -> row 8p+w (1 KB contiguous)
#pragma unroll
        for (int p = 0; p < 8; ++p) {
          const int r = 8 * p + w;
          uint4 v = *(const uint4*)&ep[r * 520 + lane * 8];
          *(uint4*)&pre2[((size_t)(m0 + 64 * st + r) << 9) + lane * 8] = v;
        }
        barrier_lds();
      }
      if (git < 39) {  // re-arm accumulators for the next m-tile
#pragma unroll
        for (int s = 0; s < 4; s++)
#pragma unroll
          for (int ms = 0; ms < 8; ms++) acc[s][ms] = (f32x4){0.f, 0.f, 0.f, 0.f};
      }
    }
  }
}

// ---------------------------------------------------------------------------
// Segment-scan LSTM (exact for any done; fast because P(reset)=0.5).
// pre2 layout: element m*512 + cell*4 + gate -> one 32B load per lane gives
// pr[r] = {i,f,g,o} of cell kcell+r.
// ---------------------------------------------------------------------------
__global__ __launch_bounds__(512) void k2a_chunk(
    const unsigned short* __restrict__ pre2, const float* __restrict__ Whh,
    const int* __restrict__ done, unsigned short* __restrict__ hidden,
    unsigned short* __restrict__ hfin, float* __restrict__ cfin) {
  __shared__ unsigned short hs[2][16 * 136];
  __shared__ int dns[LCH * 16];

  const int bg = blockIdx.x & 15;
  const int ck = blockIdx.x >> 4;
  const int t0 = ck * LCH;
  const int tid = threadIdx.x;
  const int w = tid >> 6;
  const int lane = tid & 63;
  const int l15 = lane & 15;
  const int q = lane >> 4;
  const int bglob = bg * 16 + l15;
  const int kcell = 16 * w + 4 * q;
  const int kq16 = kcell * 4;  // element offset of this lane's 4 cell-quads

  {
    const int r = tid >> 4, c = tid & 15;
    dns[tid] = done[(size_t)(t0 + r) * B_ + bg * 16 + c];
  }

  bf16x8 wf[4][4];
#pragma unroll
  for (int tI = 0; tI < 4; tI++) {
    const int jg = 16 * (w + 8 * tI) + l15;
#pragma unroll
    for (int kc = 0; kc < 4; kc++) {
      const float* p = Whh + (size_t)jg * H_ + kc * 32 + q * 8;
      float4 u0 = *(const float4*)p;
      float4 u1 = *(const float4*)(p + 4);
      bf16x8 r;
      r[0]=(short)f2bf(u0.x); r[1]=(short)f2bf(u0.y); r[2]=(short)f2bf(u0.z); r[3]=(short)f2bf(u0.w);
      r[4]=(short)f2bf(u1.x); r[5]=(short)f2bf(u1.y); r[6]=(short)f2bf(u1.z); r[7]=(short)f2bf(u1.w);
      wf[tI][kc] = r;
    }
  }

  float c_[4] = {0.f, 0.f, 0.f, 0.f};
  {
    const int b = tid >> 5, k = (tid & 31) * 4;
    *(ushort4*)&hs[0][b * 136 + k] = (ushort4){0, 0, 0, 0};
  }
  bool vld = false;
  __syncthreads();

  ushort4 pr[4], prn[4];
  load_pr(pre2 + ((size_t)t0 * B_ + bglob) * G4_ + kq16, pr);
  load_pr(pre2 + ((size_t)(t0 + 1) * B_ + bglob) * G4_ + kq16, prn);

  ushort4 hw = {0, 0, 0, 0};
#pragma unroll 1
  for (int u = 0; u < LCH; u++) {
    const int t = t0 + u;
    ushort4 pr2[4];
    const int un = (u + 2 < LCH) ? u + 2 : LCH - 1;
    load_pr(pre2 + ((size_t)(t0 + un) * B_ + bglob) * G4_ + kq16, pr2);

    const int dn = dns[u * 16 + l15];
    vld = vld || (dn != 0);

    const unsigned short* hb = hs[u & 1];
    bf16x8 hf[4];
#pragma unroll
    for (int kc = 0; kc < 4; kc++) {
      bf16x8 v = *(const bf16x8*)&hb[l15 * 136 + kc * 32 + q * 8];
      if (dn) v = (bf16x8){0, 0, 0, 0, 0, 0, 0, 0};
      hf[kc] = v;
    }

    f32x4 acc[4];
#pragma unroll
    for (int tI = 0; tI < 4; tI++) acc[tI] = (f32x4){0.f, 0.f, 0.f, 0.f};
#pragma unroll
    for (int tI = 0; tI < 4; tI++)
#pragma unroll
      for (int kc = 0; kc < 4; kc++)
        acc[tI] = __builtin_amdgcn_mfma_f32_16x16x32_bf16(
            wf[tI][kc], hf[kc], acc[tI], 0, 0, 0);

    const float m = dn ? 0.0f : 1.0f;
    float hv[4];
#pragma unroll
    for (int r = 0; r < 4; r++) {
      const float iv = acc[0][r] + bf2f(pr[r].x);
      const float fv = acc[1][r] + bf2f(pr[r].y);
      const float gv = acc[2][r] + bf2f(pr[r].z);
      const float ov = acc[3][r] + bf2f(pr[r].w);
      float cc = c_[r] * m;
      cc = sigf(fv) * cc + sigf(iv) * tanhf_(gv);
      c_[r] = cc;
      hv[r] = sigf(ov) * tanhf_(cc);
    }
    uint2 hp = {bfpack2(hv[0], hv[1]), bfpack2(hv[2], hv[3])};
    hw = *(ushort4*)&hp;
    *(uint2*)&hs[(u + 1) & 1][l15 * 136 + kcell] = hp;
    if (vld)
      *(uint2*)&hidden[((size_t)t * B_ + bglob) * H_ + kcell] = hp;
#pragma unroll
    for (int tI = 0; tI < 4; tI++) { pr[tI] = prn[tI]; prn[tI] = pr2[tI]; }
    barrier_lds();
  }

  *(ushort4*)&hfin[((size_t)ck * B_ + bglob) * H_ + kcell] = hw;
  float4 cv = {c_[0], c_[1], c_[2], c_[3]};
  *(float4*)&cfin[((size_t)ck * B_ + bglob) * H_ + kcell] = cv;
}

__global__ __launch_bounds__(512) void k2b_par(
    const unsigned short* __restrict__ pre2, const float* __restrict__ Whh,
    const float* __restrict__ h0, const float* __restrict__ c0,
    const int* __restrict__ done, unsigned short* __restrict__ hidden,
    const unsigned short* __restrict__ hfin, const float* __restrict__ cfin,
    int* __restrict__ needfix) {
  __shared__ unsigned short hs[2][16 * 136];
  __shared__ int dns[LCH * 16];

  const int bg = blockIdx.x & 15;
  const int ck = blockIdx.x >> 4;
  const int t0 = ck * LCH;
  const int tid = threadIdx.x;
  const int w = tid >> 6;
  const int lane = tid & 63;
  const int l15 = lane & 15;
  const int q = lane >> 4;
  const int bglob = bg * 16 + l15;
  const int kcell = 16 * w + 4 * q;
  const int kq16 = kcell * 4;

  {
    const int r = tid >> 4, c = tid & 15;
    dns[tid] = done[(size_t)(t0 + r) * B_ + bg * 16 + c];
  }

  bf16x8 wf[4][4];
#pragma unroll
  for (int tI = 0; tI < 4; tI++) {
    const int jg = 16 * (w + 8 * tI) + l15;
#pragma unroll
    for (int kc = 0; kc < 4; kc++) {
      const float* p = Whh + (size_t)jg * H_ + kc * 32 + q * 8;
      float4 u0 = *(const float4*)p;
      float4 u1 = *(const float4*)(p + 4);
      bf16x8 r;
      r[0]=(short)f2bf(u0.x); r[1]=(short)f2bf(u0.y); r[2]=(short)f2bf(u0.z); r[3]=(short)f2bf(u0.w);
      r[4]=(short)f2bf(u1.x); r[5]=(short)f2bf(u1.y); r[6]=(short)f2bf(u1.z); r[7]=(short)f2bf(u1.w);
      wf[tI][kc] = r;
    }
  }

  float c_[4];
  {
    const int b = tid >> 5, k = (tid & 31) * 4;
    if (ck == 0) {
      float4 hv = *(const float4*)(h0 + (size_t)(bg * 16 + b) * H_ + k);
      uint2 hp = {bfpack2(hv.x, hv.y), bfpack2(hv.z, hv.w)};
      *(uint2*)&hs[0][b * 136 + k] = hp;
      float4 cv = *(const float4*)(c0 + (size_t)bglob * H_ + kcell);
      c_[0] = cv.x; c_[1] = cv.y; c_[2] = cv.z; c_[3] = cv.w;
    } else {
      ushort4 hv = *(const ushort4*)&hfin[((size_t)(ck - 1) * B_ + bg * 16 + b) * H_ + k];
      *(ushort4*)&hs[0][b * 136 + k] = hv;
      float4 cv = *(const float4*)&cfin[((size_t)(ck - 1) * B_ + bglob) * H_ + kcell];
      c_[0] = cv.x; c_[1] = cv.y; c_[2] = cv.z; c_[3] = cv.w;
    }
  }
  int cur = 0;
  bool act = true;
  __syncthreads();

  ushort4 pr[4];
  load_pr(pre2 + ((size_t)t0 * B_ + bglob) * G4_ + kq16, pr);

#pragma unroll 1
  for (int u = 0; u < LCH; u++) {
    const int t = t0 + u;
    const int dn = dns[u * 16 + l15];
    const bool nact = act && (dn == 0);
    if (__ballot(nact) == 0ULL) { act = false; break; }
    act = nact;

    ushort4 prn[4];
    const int un = (u + 1 < LCH) ? u + 1 : LCH - 1;
    load_pr(pre2 + ((size_t)(t0 + un) * B_ + bglob) * G4_ + kq16, prn);

    const unsigned short* hb = hs[cur];
    bf16x8 hf[4];
#pragma unroll
    for (int kc = 0; kc < 4; kc++)
      hf[kc] = *(const bf16x8*)&hb[l15 * 136 + kc * 32 + q * 8];

    f32x4 acc[4];
#pragma unroll
    for (int tI = 0; tI < 4; tI++) acc[tI] = (f32x4){0.f, 0.f, 0.f, 0.f};
#pragma unroll
    for (int tI = 0; tI < 4; tI++)
#pragma unroll
      for (int kc = 0; kc < 4; kc++)
        acc[tI] = __builtin_amdgcn_mfma_f32_16x16x32_bf16(
            wf[tI][kc], hf[kc], acc[tI], 0, 0, 0);

    float hv[4];
#pragma unroll
    for (int r = 0; r < 4; r++) {
      const float iv = acc[0][r] + bf2f(pr[r].x);
      const float fv = acc[1][r] + bf2f(pr[r].y);
      const float gv = acc[2][r] + bf2f(pr[r].z);
      const float ov = acc[3][r] + bf2f(pr[r].w);
      float cc = sigf(fv) * c_[r] + sigf(iv) * tanhf_(gv);
      c_[r] = cc;
      hv[r] = sigf(ov) * tanhf_(cc);
    }
    uint2 hp = {bfpack2(hv[0], hv[1]), bfpack2(hv[2], hv[3])};
    *(uint2*)&hs[cur ^ 1][l15 * 136 + kcell] = hp;
    if (act)
      *(uint2*)&hidden[((size_t)t * B_ + bglob) * H_ + kcell] = hp;
#pragma unroll
    for (int tI = 0; tI < 4; tI++) pr[tI] = prn[tI];
    barrier_lds();
    cur ^= 1;
  }

  if (tid == 0) needfix[blockIdx.x] = (__ballot(act) != 0ULL) ? 1 : 0;
}

// Sequential guard: exact fallback, expected to exit immediately.
__global__ __launch_bounds__(512) void k2c_guard(
    const unsigned short* __restrict__ pre2, const float* __restrict__ Whh,
    const float* __restrict__ h0, const float* __restrict__ c0,
    const int* __restrict__ done, unsigned short* __restrict__ hidden,
    const unsigned short* __restrict__ hfin, const float* __restrict__ cfin,
    const int* __restrict__ needfix) {
  const int bg = blockIdx.x;
  bool dirty = false;
  for (int c2 = 0; c2 < NCH - 1; c2++) dirty |= (needfix[c2 * 16 + bg] != 0);
  if (!dirty) return;

  __shared__ unsigned short hs[2][16 * 136];
  __shared__ int dns[T_ * 16];

  const int tid = threadIdx.x;
  const int w = tid >> 6;
  const int lane = tid & 63;
  const int l15 = lane & 15;
  const int q = lane >> 4;
  const int bglob = bg * 16 + l15;
  const int kcell = 16 * w + 4 * q;
  const int kq16 = kcell * 4;

  {
    const int* p = done + (size_t)tid * B_ + bg * 16;
    *(int4*)&dns[tid * 16]      = *(const int4*)(p);
    *(int4*)&dns[tid * 16 + 4]  = *(const int4*)(p + 4);
    *(int4*)&dns[tid * 16 + 8]  = *(const int4*)(p + 8);
    *(int4*)&dns[tid * 16 + 12] = *(const int4*)(p + 12);
  }

  bf16x8 wf[4][4];
#pragma unroll
  for (int tI = 0; tI < 4; tI++) {
    const int jg = 16 * (w + 8 * tI) + l15;
#pragma unroll
    for (int kc = 0; kc < 4; kc++) {
      const float* p = Whh + (size_t)jg * H_ + kc * 32 + q * 8;
      float4 u0 = *(const float4*)p;
      float4 u1 = *(const float4*)(p + 4);
      bf16x8 r;
      r[0]=(short)f2bf(u0.x); r[1]=(short)f2bf(u0.y); r[2]=(short)f2bf(u0.z); r[3]=(short)f2bf(u0.w);
      r[4]=(short)f2bf(u1.x); r[5]=(short)f2bf(u1.y); r[6]=(short)f2bf(u1.z); r[7]=(short)f2bf(u1.w);
      wf[tI][kc] = r;
    }
  }

  float c_[4];
  {
    float4 cv = *(const float4*)(c0 + (size_t)bglob * H_ + kcell);
    c_[0] = cv.x; c_[1] = cv.y; c_[2] = cv.z; c_[3] = cv.w;
    const int b = tid >> 5, k = (tid & 31) * 4;
    float4 hv = *(const float4*)(h0 + (size_t)(bg * 16 + b) * H_ + k);
    uint2 hp = {bfpack2(hv.x, hv.y), bfpack2(hv.z, hv.w)};
    *(uint2*)&hs[0][b * 136 + k] = hp;
  }
  int cur = 0;
  __syncthreads();

#pragma unroll 1
  for (int ck = 0; ck < NCH; ck++) {
    const int t0 = ck * LCH;
    bool act = true;

    ushort4 pr[4];
    load_pr(pre2 + ((size_t)t0 * B_ + bglob) * G4_ + kq16, pr);

#pragma unroll 1
    for (int u = 0; u < LCH; u++) {
      const int t = t0 + u;
      const int dn = dns[t * 16 + l15];
      const bool nact = act && (dn == 0);
      if (__ballot(nact) == 0ULL) { act = false; break; }
      act = nact;

      ushort4 prn[4];
      const int un = (u + 1 < LCH) ? u + 1 : LCH - 1;
      load_pr(pre2 + ((size_t)(t0 + un) * B_ + bglob) * G4_ + kq16, prn);

      const unsigned short* hb = hs[cur];
      bf16x8 hf[4];
#pragma unroll
      for (int kc = 0; kc < 4; kc++)
        hf[kc] = *(const bf16x8*)&hb[l15 * 136 + kc * 32 + q * 8];

      f32x4 acc[4];
#pragma unroll
      for (int tI = 0; tI < 4; tI++) acc[tI] = (f32x4){0.f, 0.f, 0.f, 0.f};
#pragma unroll
      for (int tI = 0; tI < 4; tI++)
#pragma unroll
        for (int kc = 0; kc < 4; kc++)
          acc[tI] = __builtin_amdgcn_mfma_f32_16x16x32_bf16(
              wf[tI][kc], hf[kc], acc[tI], 0, 0, 0);

      float hv[4];
#pragma unroll
      for (int r = 0; r < 4; r++) {
        const float iv = acc[0][r] + bf2f(pr[r].x);
        const float fv = acc[1][r] + bf2f(pr[r].y);
        const float gv = acc[2][r] + bf2f(pr[r].z);
        const float ov = acc[3][r] + bf2f(pr[r].w);
        float cc = sigf(fv) * c_[r] + sigf(iv) * tanhf_(gv);
        c_[r] = cc;
        hv[r] = sigf(ov) * tanhf_(cc);
      }
      uint2 hp = {bfpack2(hv[0], hv[1]), bfpack2(hv[2], hv[3])};
      *(uint2*)&hs[cur ^ 1][l15 * 136 + kcell] = hp;
      if (act)
        *(uint2*)&hidden[((size_t)t * B_ + bglob) * H_ + kcell] = hp;
#pragma unroll
      for (int tI = 0; tI < 4; tI++) pr[tI] = prn[tI];
      barrier_lds();
      cur ^= 1;
    }

    if (!act) {
      ushort4 hv = *(const ushort4*)&hfin[((size_t)ck * B_ + bglob) * H_ + kcell];
      float4 cv = *(const float4*)&cfin[((size_t)ck * B_ + bglob) * H_ + kcell];
      c_[0] = cv.x; c_[1] = cv.y; c_[2] = cv.z; c_[3] = cv.w;
      *(ushort4*)&hs[cur][l15 * 136 + kcell] = hv;
    }
    barrier_lds();
  }
}

// ---------------------------------------------------------------------------
// K3: out[T*B][13] = hidden @ [W_pi; W_v]^T + [b_pi; b_v]   (unchanged)
// ---------------------------------------------------------------------------
__global__ __launch_bounds__(256) void k3_head(
    const unsigned short* __restrict__ hidden, const float* __restrict__ Wpi,
    const float* __restrict__ bpi, const float* __restrict__ Wv,
    const float* __restrict__ bv, float* __restrict__ out) {
  __shared__ unsigned short hs3[64 * 136];
  __shared__ float bias_s[16];

  const int tid = threadIdx.x;
  const int w = tid >> 6;
  const int lane = tid & 63;
  const int l15 = lane & 15;
  const int q = lane >> 4;
  const int m0 = blockIdx.x * 64;

  if (tid < 16) bias_s[tid] = (tid < 12) ? bpi[tid] : ((tid == 12) ? bv[0] : 0.f);

  bf16x8 wf3[4];
#pragma unroll
  for (int kc = 0; kc < 4; kc++) {
    float4 u0 = {0.f, 0.f, 0.f, 0.f}, u1 = {0.f, 0.f, 0.f, 0.f};
    if (l15 < 12) {
      const float* p = Wpi + (size_t)l15 * H_ + kc * 32 + q * 8;
      u0 = *(const float4*)p; u1 = *(const float4*)(p + 4);
    } else if (l15 == 12) {
      const float* p = Wv + kc * 32 + q * 8;
      u0 = *(const float4*)p; u1 = *(const float4*)(p + 4);
    }
    bf16x8 r;
    r[0]=(short)f2bf(u0.x); r[1]=(short)f2bf(u0.y); r[2]=(short)f2bf(u0.z); r[3]=(short)f2bf(u0.w);
    r[4]=(short)f2bf(u1.x); r[5]=(short)f2bf(u1.y); r[6]=(short)f2bf(u1.z); r[7]=(short)f2bf(u1.w);
    wf3[kc] = r;
  }

  {
    const int row = tid >> 2, ks = (tid & 3) * 32;
    const unsigned short* p = hidden + (size_t)(m0 + row) * H_ + ks;
#pragma unroll
    for (int i = 0; i < 4; i++)
      *(uint4*)&hs3[row * 136 + ks + i * 8] = *(const uint4*)(p + i * 8);
  }
  __syncthreads();

  f32x4 acc = (f32x4){0.f, 0.f, 0.f, 0.f};
#pragma unroll
  for (int kc = 0; kc < 4; kc++) {
    bf16x8 hf = *(bf16x8*)&hs3[(16 * w + l15) * 136 + kc * 32 + q * 8];
    acc = __builtin_amdgcn_mfma_f32_16x16x32_bf16(wf3[kc], hf, acc, 0, 0, 0);
  }

  const float4 bb = *(float4*)&bias_s[4 * q];
  const int m = m0 + 16 * w + l15;
  const size_t ro = (size_t)m * 13;
  float v0 = acc[0] + bb.x, v1 = acc[1] + bb.y, v2 = acc[2] + bb.z, v3 = acc[3] + bb.w;
  if (q < 3) {
    out[ro + 4 * q + 0] = v0;
    out[ro + 4 * q + 1] = v1;
    out[ro + 4 * q + 2] = v2;
    out[ro + 4 * q + 3] = v3;
  } else {
    out[ro + 12] = v0;
  }
}

// ---------------------------------------------------------------------------
// Workspace (ws, 167.8 MB):
//   pre2   bf16 [131072][512] @ 0            (cell-major-quad layout)
//   hidden bf16 [131072][128] @ 134,217,728
// Scratch in d_out (6.5 MB, overwritten by K3 at the end):
//   Wf bf16 frag-major [320 KB] @ 0   bias2 fp32 [512] @ 512 KB
//   hfin @ 1 MB, cfin @ 2 MB, needfix @ 4 MB
// ---------------------------------------------------------------------------
extern "C" void kernel_launch(void* const* d_in, const int* in_sizes, int n_in,
                              void* d_out, int out_size, void* d_ws, size_t ws_size,
                              hipStream_t stream) {
  const float* x    = (const float*)d_in[0];
  const int* done   = (const int*)d_in[1];
  const float* h0   = (const float*)d_in[2];
  const float* c0   = (const float*)d_in[3];
  const float* Wih  = (const float*)d_in[4];
  const float* Whh  = (const float*)d_in[5];
  const float* bih  = (const float*)d_in[6];
  const float* bhh  = (const float*)d_in[7];
  const float* Wpi  = (const float*)d_in[8];
  const float* bpi  = (const float*)d_in[9];
  const float* Wv   = (const float*)d_in[10];
  const float* bv   = (const float*)d_in[11];
  (void)in_sizes; (void)n_in; (void)out_size; (void)ws_size;

  unsigned short* pre2 = (unsigned short*)d_ws;
  unsigned short* hidden = pre2 + (size_t)TB_ * G4_;
  unsigned short* Wf   = (unsigned short*)d_out;
  float* bias2         = (float*)((char*)d_out + (512u << 10));
  unsigned short* hfin = (unsigned short*)((char*)d_out + (1u << 20));
  float* cfin          = (float*)((char*)d_out + (2u << 20));
  int* needfix         = (int*)((char*)d_out + (4u << 20));
  float* out = (float*)d_out;

  k0w_cvt<<<80, 256, 0, stream>>>(Wih, bih, bhh, Wf, bias2);
  k1_pregemm<<<256, 512, 0, stream>>>(x, Wf, bias2, pre2);
  k2a_chunk<<<256, 512, 0, stream>>>(pre2, Whh, done, hidden, hfin, cfin);
  k2b_par<<<256, 512, 0, stream>>>(pre2, Whh, h0, c0, done, hidden, hfin, cfin, needfix);
  k2c_guard<<<16, 512, 0, stream>>>(pre2, Whh, h0, c0, done, hidden, hfin, cfin, needfix);
  k3_head<<<TB_ / 64, 256, 0, stream>>>(hidden, Wpi, bpi, Wv, bv, out);
}

// Round 3
// 380.498 us; speedup vs baseline: 1.1326x; 1.0523x over previous
//
#include <hip/hip_runtime.h>
#include <stdint.h>
#include <stddef.h>

// Problem constants
#define T_ 512
#define B_ 256
#define IN_ 292
#define H_ 128
#define G4_ 512     // 4*H
#define TB_ 131072  // T_*B_
#define LCH 32      // time-chunk length for the segment scan
#define NCH 16      // number of chunks (T_/LCH)
#define KP_ 320     // K padded to 10*32

typedef short bf16x8 __attribute__((ext_vector_type(8)));
typedef float f32x4 __attribute__((ext_vector_type(4)));

__device__ __forceinline__ unsigned short f2bf(float f) {
  unsigned u = __float_as_uint(f);
  u += 0x7FFFu + ((u >> 16) & 1u);   // RTNE
  return (unsigned short)(u >> 16);
}
__device__ __forceinline__ float bf2f(unsigned short s) {
  return __uint_as_float(((unsigned)s) << 16);
}
// two fp32 -> packed bf16 pair (round-half-up). 1.5 VALU ops/elem.
__device__ __forceinline__ unsigned bfpack2(float a, float b) {
  unsigned ua = __float_as_uint(a) + 0x8000u;
  unsigned ub = __float_as_uint(b) + 0x8000u;
  return __builtin_amdgcn_perm(ub, ua, 0x07060302u);  // [ub.hi16 : ua.hi16]
}
__device__ __forceinline__ float sigf(float x) {
  return __builtin_amdgcn_rcpf(1.0f + __expf(-x));
}
__device__ __forceinline__ float tanhf_(float x) {
  return 1.0f - 2.0f * __builtin_amdgcn_rcpf(__expf(2.0f * x) + 1.0f);
}
// LDS-only barrier: lgkmcnt(0)+s_barrier, leaves global loads/stores in flight.
__device__ __forceinline__ void barrier_lds() {
  asm volatile("s_waitcnt lgkmcnt(0)\n\ts_barrier" ::: "memory");
}
// async 16B global->LDS (direct-to-LDS DMA, no VGPR round trip)
__device__ __forceinline__ void gload_lds16(const float* g, float* l) {
  __builtin_amdgcn_global_load_lds(
      (const __attribute__((address_space(1))) void*)g,
      (__attribute__((address_space(3))) void*)l, 16, 0, 0);
}
// load one lane's 4 cell-quads (32 B contiguous): pr[r] = {i,f,g,o} of cell r.
__device__ __forceinline__ void load_pr(const unsigned short* p, ushort4* pr) {
  union { uint4 v; ushort4 s[2]; } a, b;
  a.v = *(const uint4*)p;
  b.v = *(const uint4*)(p + 8);
  pr[0] = a.s[0]; pr[1] = a.s[1]; pr[2] = b.s[0]; pr[3] = b.s[1];
}

// ---------------------------------------------------------------------------
// K0w v3: W_ih fp32 [512][292] -> Wf, FRAG-MAJOR bf16 layout:
//   Wf[((g16*10 + it)*64 + lane)*8 .. +8] = row jj = 16*g16 + (lane&15),
//   k = it*32 + (lane>>4)*8 .. +8, with jj -> W_ih row (jj&3)*128 + (jj>>2)
//   (jj = cell*4 + gate). Each k1 af-load is 64 lanes x 16B fully contiguous.
//   Zero-pads k 292..319. Also emits reordered bias2[jj] fp32.
// ---------------------------------------------------------------------------
__global__ __launch_bounds__(256) void k0w_cvt(
    const float* __restrict__ Wih, const float* __restrict__ bih,
    const float* __restrict__ bhh, unsigned short* __restrict__ Wf,
    float* __restrict__ bias2) {
  const int g = blockIdx.x * 256 + threadIdx.x;  // 0..20479
  const int lane = g & 63;
  const int rest = g >> 6;          // 0..319
  const int it = rest % 10;
  const int g16 = rest / 10;        // 0..31
  const int jj = g16 * 16 + (lane & 15);
  const int src = (jj & 3) * 128 + (jj >> 2);
  const int c0 = it * 32 + (lane >> 4) * 8;
  if (g < 512) {
    const int sb = (g & 3) * 128 + (g >> 2);
    bias2[g] = bih[sb] + bhh[sb];
  }
  float4 a = {0.f, 0.f, 0.f, 0.f}, b = {0.f, 0.f, 0.f, 0.f};
  const float* p = Wih + (size_t)src * IN_ + c0;
  if (c0 + 8 <= IN_) { a = *(const float4*)p; b = *(const float4*)(p + 4); }
  else if (c0 < IN_) { a = *(const float4*)p; }  // c0==288: cols 288..291
  uint4 o;
  o.x = bfpack2(a.x, a.y); o.y = bfpack2(a.z, a.w);
  o.z = bfpack2(b.x, b.y); o.w = bfpack2(b.z, b.w);
  *(uint4*)&Wf[(size_t)g * 8] = o;  // g == (g16*10+it)*64 + lane
}

// ---------------------------------------------------------------------------
// K1 v5: pre2[m][jj] (bf16) = x @ W^T + bias2.
// Round-2 post-mortem fixes:
//  - x register ring DELETED (runtime-indexed vector arrays -> scratch, and
//    the in-order vmcnt queue meant any W-wait drained the x stream anyway).
//  - x staged fp32 straight to LDS via global_load_lds (double-buffered,
//    1 tile ahead); bf16 conversion happens at fragment build (cheap VALU).
//  - LDS row stride 128B would be a 16-way bank conflict: both-sides XOR
//    swizzle (rule #21): 16B-quad p of row r holds true quad p^(r&7);
//    global SOURCE address pre-swizzled (LDS dest linear, as gload_lds
//    requires); frag read applies the same XOR -> 2 lanes/bank (free).
//  - __syncthreads() in main loop (drains the 1-ahead gload; bounded cost);
//    epilogue barriers stay lgkm-only so pre2 stores remain in flight.
//  - tail k-tile (k=288..291): exec-masked gload on the single real quad;
//    other quads keep stale LDS data which multiplies zero-padded W.
// ---------------------------------------------------------------------------
__device__ __forceinline__ void k1_stage(
    const float* __restrict__ x, float* ldsbuf, int bid4, int g2,
    int w, int lane) {
  const int jx = g2 / 10, kt = g2 % 10;
#pragma unroll
  for (int j = 0; j < 2; ++j) {
    const int r = w * 16 + j * 8 + (lane >> 3);       // tile row 0..127
    const int tq = (lane & 7) ^ (r & 7);              // true 16B-quad index
    const float* src =
        x + (size_t)((bid4 + jx) * 128 + r) * IN_ + kt * 32 + tq * 4;
    float* dst = ldsbuf + w * 512 + j * 256;          // wave-uniform base
    if (kt < 9 || tq == 0) gload_lds16(src, dst);
  }
}

__global__ __launch_bounds__(512, 2) void k1_pregemm(
    const float* __restrict__ x, const unsigned short* __restrict__ Wf,
    const float* __restrict__ bias2, unsigned short* __restrict__ pre2) {
  __shared__ float xtf[2][128 * 32];          // 2 x 16 KB fp32 x tiles
  __shared__ unsigned short ep[64 * 520];     // 65 KB epilogue staging

  const int tid = threadIdx.x;
  const int w = tid >> 6;        // 0..7: jj group [64w, 64w+64)
  const int lane = tid & 63;
  const int l15 = lane & 15;
  const int q = lane >> 4;
  const int bid4 = blockIdx.x * 4;

  // W frag base for this wave: af(s,it) at wfbase + (s*10+it)*512 ushorts
  const unsigned short* wfbase = Wf + ((size_t)(4 * w) * 10 * 64 + lane) * 8;

  f32x4 acc[4][8];
#pragma unroll
  for (int s = 0; s < 4; s++)
#pragma unroll
    for (int ms = 0; ms < 8; ms++) acc[s][ms] = (f32x4){0.f, 0.f, 0.f, 0.f};

  // prologue: stage tile 0, load W frags for tile 0
  k1_stage(x, &xtf[0][0], bid4, 0, w, lane);
  bf16x8 af[4];
#pragma unroll
  for (int s = 0; s < 4; s++)
    af[s] = *(const bf16x8*)(wfbase + (s * 10 + 0) * 512);
  __syncthreads();

#pragma unroll 1
  for (int git = 0; git < 40; ++git) {
    const int kt = git % 10;
    // 1) prefetch next-iter W frags (L2-hot; arrives by next barrier)
    bf16x8 afn[4];
    if (git < 39) {
      const int nit = (kt == 9) ? 0 : kt + 1;
#pragma unroll
      for (int s = 0; s < 4; s++)
        afn[s] = *(const bf16x8*)(wfbase + (s * 10 + nit) * 512);
    }
    // 2) fragments from fp32 LDS (swizzled read) + convert to bf16
    const float* xb = &xtf[git & 1][0];
    bf16x8 bfr[8];
#pragma unroll
    for (int ms = 0; ms < 8; ms++) {
      const int r = 16 * ms + l15;
      const int a0 = (2 * q) ^ (r & 7), a1 = (2 * q + 1) ^ (r & 7);
      const float4 u0 = *(const float4*)&xb[r * 32 + a0 * 4];
      const float4 u1 = *(const float4*)&xb[r * 32 + a1 * 4];
      union { unsigned u[4]; bf16x8 v; } cv;
      cv.u[0] = bfpack2(u0.x, u0.y); cv.u[1] = bfpack2(u0.z, u0.w);
      cv.u[2] = bfpack2(u1.x, u1.y); cv.u[3] = bfpack2(u1.z, u1.w);
      bfr[ms] = cv.v;
    }
    // 3) stage next x tile into the other buffer (drained at barrier)
    if (git < 39) k1_stage(x, &xtf[(git + 1) & 1][0], bid4, git + 1, w, lane);
    // 4) 32 MFMA
#pragma unroll
    for (int s = 0; s < 4; s++)
#pragma unroll
      for (int ms = 0; ms < 8; ms++)
        acc[s][ms] = __builtin_amdgcn_mfma_f32_16x16x32_bf16(
            af[s], bfr[ms], acc[s][ms], 0, 0, 0);
#pragma unroll
    for (int s = 0; s < 4; s++) af[s] = afn[s];
    __syncthreads();

    if (kt == 9) {
      // -------- epilogue for m-tile j = git/10: rows m0..m0+127 ----------
      const int m0 = (bid4 + git / 10) * 128;
      float4 bb[4];
#pragma unroll
      for (int s = 0; s < 4; s++)
        bb[s] = *(const float4*)&bias2[64 * w + 16 * s + 4 * q];
#pragma unroll
      for (int st = 0; st < 2; ++st) {
        // every wave writes its jj-cols for rows [64st, 64st+64)
#pragma unroll
        for (int mm = 0; mm < 4; ++mm) {
          const int ms = 4 * st + mm;
#pragma unroll
          for (int s = 0; s < 4; ++s) {
            uint2 v;
            v.x = bfpack2(acc[s][ms][0] + bb[s].x, acc[s][ms][1] + bb[s].y);
            v.y = bfpack2(acc[s][ms][2] + bb[s].z, acc[s][ms][3] + bb[s].w);
            *(uint2*)&ep[(16 * mm + l15) * 520 + 64 * w + 16 * s + 4 * q] = v;
          }
        }
        barrier_lds();
        // full-row stores: wave w, pass p -> row 8p+w (1 KB contiguous)
#pragma unroll
        for (int p = 0; p < 8; ++p) {
          const int r = 8 * p + w;
          uint4 v = *(const uint4*)&ep[r * 520 + lane * 8];
          *(uint4*)&pre2[((size_t)(m0 + 64 * st + r) << 9) + lane * 8] = v;
        }
        barrier_lds();
      }
      if (git < 39) {  // re-arm accumulators for the next m-tile
#pragma unroll
        for (int s = 0; s < 4; s++)
#pragma unroll
          for (int ms = 0; ms < 8; ms++) acc[s][ms] = (f32x4){0.f, 0.f, 0.f, 0.f};
      }
    }
  }
}

// ---------------------------------------------------------------------------
// Segment-scan LSTM (exact for any done; fast because P(reset)=0.5).
// pre2 layout: element m*512 + cell*4 + gate -> one 32B load per lane gives
// pr[r] = {i,f,g,o} of cell kcell+r.
// ---------------------------------------------------------------------------
__global__ __launch_bounds__(512) void k2a_chunk(
    const unsigned short* __restrict__ pre2, const float* __restrict__ Whh,
    const int* __restrict__ done, unsigned short* __restrict__ hidden,
    unsigned short* __restrict__ hfin, float* __restrict__ cfin) {
  __shared__ unsigned short hs[2][16 * 136];
  __shared__ int dns[LCH * 16];

  const int bg = blockIdx.x & 15;
  const int ck = blockIdx.x >> 4;
  const int t0 = ck * LCH;
  const int tid = threadIdx.x;
  const int w = tid >> 6;
  const int lane = tid & 63;
  const int l15 = lane & 15;
  const int q = lane >> 4;
  const int bglob = bg * 16 + l15;
  const int kcell = 16 * w + 4 * q;
  const int kq16 = kcell * 4;  // element offset of this lane's 4 cell-quads

  {
    const int r = tid >> 4, c = tid & 15;
    dns[tid] = done[(size_t)(t0 + r) * B_ + bg * 16 + c];
  }

  bf16x8 wf[4][4];
#pragma unroll
  for (int tI = 0; tI < 4; tI++) {
    const int jg = 16 * (w + 8 * tI) + l15;
#pragma unroll
    for (int kc = 0; kc < 4; kc++) {
      const float* p = Whh + (size_t)jg * H_ + kc * 32 + q * 8;
      float4 u0 = *(const float4*)p;
      float4 u1 = *(const float4*)(p + 4);
      bf16x8 r;
      r[0]=(short)f2bf(u0.x); r[1]=(short)f2bf(u0.y); r[2]=(short)f2bf(u0.z); r[3]=(short)f2bf(u0.w);
      r[4]=(short)f2bf(u1.x); r[5]=(short)f2bf(u1.y); r[6]=(short)f2bf(u1.z); r[7]=(short)f2bf(u1.w);
      wf[tI][kc] = r;
    }
  }

  float c_[4] = {0.f, 0.f, 0.f, 0.f};
  {
    const int b = tid >> 5, k = (tid & 31) * 4;
    *(ushort4*)&hs[0][b * 136 + k] = (ushort4){0, 0, 0, 0};
  }
  bool vld = false;
  __syncthreads();

  ushort4 pr[4], prn[4];
  load_pr(pre2 + ((size_t)t0 * B_ + bglob) * G4_ + kq16, pr);
  load_pr(pre2 + ((size_t)(t0 + 1) * B_ + bglob) * G4_ + kq16, prn);

  ushort4 hw = {0, 0, 0, 0};
#pragma unroll 1
  for (int u = 0; u < LCH; u++) {
    const int t = t0 + u;
    ushort4 pr2[4];
    const int un = (u + 2 < LCH) ? u + 2 : LCH - 1;
    load_pr(pre2 + ((size_t)(t0 + un) * B_ + bglob) * G4_ + kq16, pr2);

    const int dn = dns[u * 16 + l15];
    vld = vld || (dn != 0);

    const unsigned short* hb = hs[u & 1];
    bf16x8 hf[4];
#pragma unroll
    for (int kc = 0; kc < 4; kc++) {
      bf16x8 v = *(const bf16x8*)&hb[l15 * 136 + kc * 32 + q * 8];
      if (dn) v = (bf16x8){0, 0, 0, 0, 0, 0, 0, 0};
      hf[kc] = v;
    }

    f32x4 acc[4];
#pragma unroll
    for (int tI = 0; tI < 4; tI++) acc[tI] = (f32x4){0.f, 0.f, 0.f, 0.f};
#pragma unroll
    for (int tI = 0; tI < 4; tI++)
#pragma unroll
      for (int kc = 0; kc < 4; kc++)
        acc[tI] = __builtin_amdgcn_mfma_f32_16x16x32_bf16(
            wf[tI][kc], hf[kc], acc[tI], 0, 0, 0);

    const float m = dn ? 0.0f : 1.0f;
    float hv[4];
#pragma unroll
    for (int r = 0; r < 4; r++) {
      const float iv = acc[0][r] + bf2f(pr[r].x);
      const float fv = acc[1][r] + bf2f(pr[r].y);
      const float gv = acc[2][r] + bf2f(pr[r].z);
      const float ov = acc[3][r] + bf2f(pr[r].w);
      float cc = c_[r] * m;
      cc = sigf(fv) * cc + sigf(iv) * tanhf_(gv);
      c_[r] = cc;
      hv[r] = sigf(ov) * tanhf_(cc);
    }
    uint2 hp = {bfpack2(hv[0], hv[1]), bfpack2(hv[2], hv[3])};
    hw = *(ushort4*)&hp;
    *(uint2*)&hs[(u + 1) & 1][l15 * 136 + kcell] = hp;
    if (vld)
      *(uint2*)&hidden[((size_t)t * B_ + bglob) * H_ + kcell] = hp;
#pragma unroll
    for (int tI = 0; tI < 4; tI++) { pr[tI] = prn[tI]; prn[tI] = pr2[tI]; }
    barrier_lds();
  }

  *(ushort4*)&hfin[((size_t)ck * B_ + bglob) * H_ + kcell] = hw;
  float4 cv = {c_[0], c_[1], c_[2], c_[3]};
  *(float4*)&cfin[((size_t)ck * B_ + bglob) * H_ + kcell] = cv;
}

__global__ __launch_bounds__(512) void k2b_par(
    const unsigned short* __restrict__ pre2, const float* __restrict__ Whh,
    const float* __restrict__ h0, const float* __restrict__ c0,
    const int* __restrict__ done, unsigned short* __restrict__ hidden,
    const unsigned short* __restrict__ hfin, const float* __restrict__ cfin,
    int* __restrict__ needfix) {
  __shared__ unsigned short hs[2][16 * 136];
  __shared__ int dns[LCH * 16];

  const int bg = blockIdx.x & 15;
  const int ck = blockIdx.x >> 4;
  const int t0 = ck * LCH;
  const int tid = threadIdx.x;
  const int w = tid >> 6;
  const int lane = tid & 63;
  const int l15 = lane & 15;
  const int q = lane >> 4;
  const int bglob = bg * 16 + l15;
  const int kcell = 16 * w + 4 * q;
  const int kq16 = kcell * 4;

  {
    const int r = tid >> 4, c = tid & 15;
    dns[tid] = done[(size_t)(t0 + r) * B_ + bg * 16 + c];
  }

  bf16x8 wf[4][4];
#pragma unroll
  for (int tI = 0; tI < 4; tI++) {
    const int jg = 16 * (w + 8 * tI) + l15;
#pragma unroll
    for (int kc = 0; kc < 4; kc++) {
      const float* p = Whh + (size_t)jg * H_ + kc * 32 + q * 8;
      float4 u0 = *(const float4*)p;
      float4 u1 = *(const float4*)(p + 4);
      bf16x8 r;
      r[0]=(short)f2bf(u0.x); r[1]=(short)f2bf(u0.y); r[2]=(short)f2bf(u0.z); r[3]=(short)f2bf(u0.w);
      r[4]=(short)f2bf(u1.x); r[5]=(short)f2bf(u1.y); r[6]=(short)f2bf(u1.z); r[7]=(short)f2bf(u1.w);
      wf[tI][kc] = r;
    }
  }

  float c_[4];
  {
    const int b = tid >> 5, k = (tid & 31) * 4;
    if (ck == 0) {
      float4 hv = *(const float4*)(h0 + (size_t)(bg * 16 + b) * H_ + k);
      uint2 hp = {bfpack2(hv.x, hv.y), bfpack2(hv.z, hv.w)};
      *(uint2*)&hs[0][b * 136 + k] = hp;
      float4 cv = *(const float4*)(c0 + (size_t)bglob * H_ + kcell);
      c_[0] = cv.x; c_[1] = cv.y; c_[2] = cv.z; c_[3] = cv.w;
    } else {
      ushort4 hv = *(const ushort4*)&hfin[((size_t)(ck - 1) * B_ + bg * 16 + b) * H_ + k];
      *(ushort4*)&hs[0][b * 136 + k] = hv;
      float4 cv = *(const float4*)&cfin[((size_t)(ck - 1) * B_ + bglob) * H_ + kcell];
      c_[0] = cv.x; c_[1] = cv.y; c_[2] = cv.z; c_[3] = cv.w;
    }
  }
  int cur = 0;
  bool act = true;
  __syncthreads();

  ushort4 pr[4];
  load_pr(pre2 + ((size_t)t0 * B_ + bglob) * G4_ + kq16, pr);

#pragma unroll 1
  for (int u = 0; u < LCH; u++) {
    const int t = t0 + u;
    const int dn = dns[u * 16 + l15];
    const bool nact = act && (dn == 0);
    if (__ballot(nact) == 0ULL) { act = false; break; }
    act = nact;

    ushort4 prn[4];
    const int un = (u + 1 < LCH) ? u + 1 : LCH - 1;
    load_pr(pre2 + ((size_t)(t0 + un) * B_ + bglob) * G4_ + kq16, prn);

    const unsigned short* hb = hs[cur];
    bf16x8 hf[4];
#pragma unroll
    for (int kc = 0; kc < 4; kc++)
      hf[kc] = *(const bf16x8*)&hb[l15 * 136 + kc * 32 + q * 8];

    f32x4 acc[4];
#pragma unroll
    for (int tI = 0; tI < 4; tI++) acc[tI] = (f32x4){0.f, 0.f, 0.f, 0.f};
#pragma unroll
    for (int tI = 0; tI < 4; tI++)
#pragma unroll
      for (int kc = 0; kc < 4; kc++)
        acc[tI] = __builtin_amdgcn_mfma_f32_16x16x32_bf16(
            wf[tI][kc], hf[kc], acc[tI], 0, 0, 0);

    float hv[4];
#pragma unroll
    for (int r = 0; r < 4; r++) {
      const float iv = acc[0][r] + bf2f(pr[r].x);
      const float fv = acc[1][r] + bf2f(pr[r].y);
      const float gv = acc[2][r] + bf2f(pr[r].z);
      const float ov = acc[3][r] + bf2f(pr[r].w);
      float cc = sigf(fv) * c_[r] + sigf(iv) * tanhf_(gv);
      c_[r] = cc;
      hv[r] = sigf(ov) * tanhf_(cc);
    }
    uint2 hp = {bfpack2(hv[0], hv[1]), bfpack2(hv[2], hv[3])};
    *(uint2*)&hs[cur ^ 1][l15 * 136 + kcell] = hp;
    if (act)
      *(uint2*)&hidden[((size_t)t * B_ + bglob) * H_ + kcell] = hp;
#pragma unroll
    for (int tI = 0; tI < 4; tI++) pr[tI] = prn[tI];
    barrier_lds();
    cur ^= 1;
  }

  if (tid == 0) needfix[blockIdx.x] = (__ballot(act) != 0ULL) ? 1 : 0;
}

// Sequential guard: exact fallback, expected to exit immediately.
__global__ __launch_bounds__(512) void k2c_guard(
    const unsigned short* __restrict__ pre2, const float* __restrict__ Whh,
    const float* __restrict__ h0, const float* __restrict__ c0,
    const int* __restrict__ done, unsigned short* __restrict__ hidden,
    const unsigned short* __restrict__ hfin, const float* __restrict__ cfin,
    const int* __restrict__ needfix) {
  const int bg = blockIdx.x;
  bool dirty = false;
  for (int c2 = 0; c2 < NCH - 1; c2++) dirty |= (needfix[c2 * 16 + bg] != 0);
  if (!dirty) return;

  __shared__ unsigned short hs[2][16 * 136];
  __shared__ int dns[T_ * 16];

  const int tid = threadIdx.x;
  const int w = tid >> 6;
  const int lane = tid & 63;
  const int l15 = lane & 15;
  const int q = lane >> 4;
  const int bglob = bg * 16 + l15;
  const int kcell = 16 * w + 4 * q;
  const int kq16 = kcell * 4;

  {
    const int* p = done + (size_t)tid * B_ + bg * 16;
    *(int4*)&dns[tid * 16]      = *(const int4*)(p);
    *(int4*)&dns[tid * 16 + 4]  = *(const int4*)(p + 4);
    *(int4*)&dns[tid * 16 + 8]  = *(const int4*)(p + 8);
    *(int4*)&dns[tid * 16 + 12] = *(const int4*)(p + 12);
  }

  bf16x8 wf[4][4];
#pragma unroll
  for (int tI = 0; tI < 4; tI++) {
    const int jg = 16 * (w + 8 * tI) + l15;
#pragma unroll
    for (int kc = 0; kc < 4; kc++) {
      const float* p = Whh + (size_t)jg * H_ + kc * 32 + q * 8;
      float4 u0 = *(const float4*)p;
      float4 u1 = *(const float4*)(p + 4);
      bf16x8 r;
      r[0]=(short)f2bf(u0.x); r[1]=(short)f2bf(u0.y); r[2]=(short)f2bf(u0.z); r[3]=(short)f2bf(u0.w);
      r[4]=(short)f2bf(u1.x); r[5]=(short)f2bf(u1.y); r[6]=(short)f2bf(u1.z); r[7]=(short)f2bf(u1.w);
      wf[tI][kc] = r;
    }
  }

  float c_[4];
  {
    float4 cv = *(const float4*)(c0 + (size_t)bglob * H_ + kcell);
    c_[0] = cv.x; c_[1] = cv.y; c_[2] = cv.z; c_[3] = cv.w;
    const int b = tid >> 5, k = (tid & 31) * 4;
    float4 hv = *(const float4*)(h0 + (size_t)(bg * 16 + b) * H_ + k);
    uint2 hp = {bfpack2(hv.x, hv.y), bfpack2(hv.z, hv.w)};
    *(uint2*)&hs[0][b * 136 + k] = hp;
  }
  int cur = 0;
  __syncthreads();

#pragma unroll 1
  for (int ck = 0; ck < NCH; ck++) {
    const int t0 = ck * LCH;
    bool act = true;

    ushort4 pr[4];
    load_pr(pre2 + ((size_t)t0 * B_ + bglob) * G4_ + kq16, pr);

#pragma unroll 1
    for (int u = 0; u < LCH; u++) {
      const int t = t0 + u;
      const int dn = dns[t * 16 + l15];
      const bool nact = act && (dn == 0);
      if (__ballot(nact) == 0ULL) { act = false; break; }
      act = nact;

      ushort4 prn[4];
      const int un = (u + 1 < LCH) ? u + 1 : LCH - 1;
      load_pr(pre2 + ((size_t)(t0 + un) * B_ + bglob) * G4_ + kq16, prn);

      const unsigned short* hb = hs[cur];
      bf16x8 hf[4];
#pragma unroll
      for (int kc = 0; kc < 4; kc++)
        hf[kc] = *(const bf16x8*)&hb[l15 * 136 + kc * 32 + q * 8];

      f32x4 acc[4];
#pragma unroll
      for (int tI = 0; tI < 4; tI++) acc[tI] = (f32x4){0.f, 0.f, 0.f, 0.f};
#pragma unroll
      for (int tI = 0; tI < 4; tI++)
#pragma unroll
        for (int kc = 0; kc < 4; kc++)
          acc[tI] = __builtin_amdgcn_mfma_f32_16x16x32_bf16(
              wf[tI][kc], hf[kc], acc[tI], 0, 0, 0);

      float hv[4];
#pragma unroll
      for (int r = 0; r < 4; r++) {
        const float iv = acc[0][r] + bf2f(pr[r].x);
        const float fv = acc[1][r] + bf2f(pr[r].y);
        const float gv = acc[2][r] + bf2f(pr[r].z);
        const float ov = acc[3][r] + bf2f(pr[r].w);
        float cc = sigf(fv) * c_[r] + sigf(iv) * tanhf_(gv);
        c_[r] = cc;
        hv[r] = sigf(ov) * tanhf_(cc);
      }
      uint2 hp = {bfpack2(hv[0], hv[1]), bfpack2(hv[2], hv[3])};
      *(uint2*)&hs[cur ^ 1][l15 * 136 + kcell] = hp;
      if (act)
        *(uint2*)&hidden[((size_t)t * B_ + bglob) * H_ + kcell] = hp;
#pragma unroll
      for (int tI = 0; tI < 4; tI++) pr[tI] = prn[tI];
      barrier_lds();
      cur ^= 1;
    }

    if (!act) {
      ushort4 hv = *(const ushort4*)&hfin[((size_t)ck * B_ + bglob) * H_ + kcell];
      float4 cv = *(const float4*)&cfin[((size_t)ck * B_ + bglob) * H_ + kcell];
      c_[0] = cv.x; c_[1] = cv.y; c_[2] = cv.z; c_[3] = cv.w;
      *(ushort4*)&hs[cur][l15 * 136 + kcell] = hv;
    }
    barrier_lds();
  }
}

// ---------------------------------------------------------------------------
// K3: out[T*B][13] = hidden @ [W_pi; W_v]^T + [b_pi; b_v]   (unchanged)
// ---------------------------------------------------------------------------
__global__ __launch_bounds__(256) void k3_head(
    const unsigned short* __restrict__ hidden, const float* __restrict__ Wpi,
    const float* __restrict__ bpi, const float* __restrict__ Wv,
    const float* __restrict__ bv, float* __restrict__ out) {
  __shared__ unsigned short hs3[64 * 136];
  __shared__ float bias_s[16];

  const int tid = threadIdx.x;
  const int w = tid >> 6;
  const int lane = tid & 63;
  const int l15 = lane & 15;
  const int q = lane >> 4;
  const int m0 = blockIdx.x * 64;

  if (tid < 16) bias_s[tid] = (tid < 12) ? bpi[tid] : ((tid == 12) ? bv[0] : 0.f);

  bf16x8 wf3[4];
#pragma unroll
  for (int kc = 0; kc < 4; kc++) {
    float4 u0 = {0.f, 0.f, 0.f, 0.f}, u1 = {0.f, 0.f, 0.f, 0.f};
    if (l15 < 12) {
      const float* p = Wpi + (size_t)l15 * H_ + kc * 32 + q * 8;
      u0 = *(const float4*)p; u1 = *(const float4*)(p + 4);
    } else if (l15 == 12) {
      const float* p = Wv + kc * 32 + q * 8;
      u0 = *(const float4*)p; u1 = *(const float4*)(p + 4);
    }
    bf16x8 r;
    r[0]=(short)f2bf(u0.x); r[1]=(short)f2bf(u0.y); r[2]=(short)f2bf(u0.z); r[3]=(short)f2bf(u0.w);
    r[4]=(short)f2bf(u1.x); r[5]=(short)f2bf(u1.y); r[6]=(short)f2bf(u1.z); r[7]=(short)f2bf(u1.w);
    wf3[kc] = r;
  }

  {
    const int row = tid >> 2, ks = (tid & 3) * 32;
    const unsigned short* p = hidden + (size_t)(m0 + row) * H_ + ks;
#pragma unroll
    for (int i = 0; i < 4; i++)
      *(uint4*)&hs3[row * 136 + ks + i * 8] = *(const uint4*)(p + i * 8);
  }
  __syncthreads();

  f32x4 acc = (f32x4){0.f, 0.f, 0.f, 0.f};
#pragma unroll
  for (int kc = 0; kc < 4; kc++) {
    bf16x8 hf = *(bf16x8*)&hs3[(16 * w + l15) * 136 + kc * 32 + q * 8];
    acc = __builtin_amdgcn_mfma_f32_16x16x32_bf16(wf3[kc], hf, acc, 0, 0, 0);
  }

  const float4 bb = *(float4*)&bias_s[4 * q];
  const int m = m0 + 16 * w + l15;
  const size_t ro = (size_t)m * 13;
  float v0 = acc[0] + bb.x, v1 = acc[1] + bb.y, v2 = acc[2] + bb.z, v3 = acc[3] + bb.w;
  if (q < 3) {
    out[ro + 4 * q + 0] = v0;
    out[ro + 4 * q + 1] = v1;
    out[ro + 4 * q + 2] = v2;
    out[ro + 4 * q + 3] = v3;
  } else {
    out[ro + 12] = v0;
  }
}

// ---------------------------------------------------------------------------
// Workspace (ws, 167.8 MB):
//   pre2   bf16 [131072][512] @ 0            (cell-major-quad layout)
//   hidden bf16 [131072][128] @ 134,217,728
// Scratch in d_out (6.5 MB, overwritten by K3 at the end):
//   Wf bf16 frag-major [320 KB] @ 0   bias2 fp32 [512] @ 512 KB
//   hfin @ 1 MB, cfin @ 2 MB, needfix @ 4 MB
// ---------------------------------------------------------------------------
extern "C" void kernel_launch(void* const* d_in, const int* in_sizes, int n_in,
                              void* d_out, int out_size, void* d_ws, size_t ws_size,
                              hipStream_t stream) {
  const float* x    = (const float*)d_in[0];
  const int* done   = (const int*)d_in[1];
  const float* h0   = (const float*)d_in[2];
  const float* c0   = (const float*)d_in[3];
  const float* Wih  = (const float*)d_in[4];
  const float* Whh  = (const float*)d_in[5];
  const float* bih  = (const float*)d_in[6];
  const float* bhh  = (const float*)d_in[7];
  const float* Wpi  = (const float*)d_in[8];
  const float* bpi  = (const float*)d_in[9];
  const float* Wv   = (const float*)d_in[10];
  const float* bv   = (const float*)d_in[11];
  (void)in_sizes; (void)n_in; (void)out_size; (void)ws_size;

  unsigned short* pre2 = (unsigned short*)d_ws;
  unsigned short* hidden = pre2 + (size_t)TB_ * G4_;
  unsigned short* Wf   = (unsigned short*)d_out;
  float* bias2         = (float*)((char*)d_out + (512u << 10));
  unsigned short* hfin = (unsigned short*)((char*)d_out + (1u << 20));
  float* cfin          = (float*)((char*)d_out + (2u << 20));
  int* needfix         = (int*)((char*)d_out + (4u << 20));
  float* out = (float*)d_out;

  k0w_cvt<<<80, 256, 0, stream>>>(Wih, bih, bhh, Wf, bias2);
  k1_pregemm<<<256, 512, 0, stream>>>(x, Wf, bias2, pre2);
  k2a_chunk<<<256, 512, 0, stream>>>(pre2, Whh, done, hidden, hfin, cfin);
  k2b_par<<<256, 512, 0, stream>>>(pre2, Whh, h0, c0, done, hidden, hfin, cfin, needfix);
  k2c_guard<<<16, 512, 0, stream>>>(pre2, Whh, h0, c0, done, hidden, hfin, cfin, needfix);
  k3_head<<<TB_ / 64, 256, 0, stream>>>(hidden, Wpi, bpi, Wv, bv, out);
}